// Round 13
// baseline (219.998 us; speedup 1.0000x reference)
//
#include <hip/hip_runtime.h>
#include <climits>

// Problem constants (fixed by the reference): B=8192 rows, D=512 features.
#define NB 8192
#define ND 512

// Band covers cols [0,BANDW); wina [WSTART, WCOLS); tail [WSTART, NB).
#define BANDW 128
#define WSTART BANDW                 // 128
#define WCHUNKS 32
#define WTILES 4
#define WCAP (WTILES * 64)           // 256 stragglers/z
#define WCOLS (WSTART + WCHUNKS * 32)  // 1152
#define TCHUNKS ((NB - WSTART) / 32)   // 252

#define PK_NONE (~0ULL)

// pack (col, lm) so u64 atomicMin selects min col; lm>0 => bits monotone.
__device__ inline unsigned long long pack_cand(int col, float lm) {
    return ((unsigned long long)(unsigned)col << 32) |
           (unsigned long long)__float_as_uint(lm);
}

// ===========================================================================
// Fast path: stats -> band -> wina -> tail -> final through d_ws.
// ws layout: floats rnImg rnTxt rnCr dgSim dgCr mgCr [6*NB];
//            u64 negIdx64 [4*NB]; int stragCnt [16]; int stragList [4*NB]
// ===========================================================================

// Per-row stats + workspace init. 16 threads/row, 16 rows/block, 512 blocks.
__global__ __launch_bounds__(256) void stats_k(
        const float* __restrict__ img, const float* __restrict__ txt,
        const float* __restrict__ cr, const float* __restrict__ margin,
        const int* __restrict__ flagp,
        float* rnImg, float* rnTxt, float* rnCr,
        float* dgSim, float* dgCr, float* mgCr,
        unsigned long long* negIdx64, int* stragCnt, float* out) {
    int tid = threadIdx.x, bid = blockIdx.x;
    int g = bid * 256 + tid;
    if (g < 4 * NB) negIdx64[g] = PK_NONE;
    if (bid == 0 && tid < 16) stragCnt[tid] = 0;
    if (bid == 0 && tid == 0) out[0] = 0.0f;

    int r = bid * 16 + (tid >> 4);
    int q = tid & 15;
    const float4* iv = (const float4*)(img + (size_t)r * ND);
    const float4* tv = (const float4*)(txt + (size_t)r * ND);
    const float4* cv = (const float4*)(cr  + (size_t)r * ND);
    float sii = 0, stt = 0, scc = 0, sit = 0, sic = 0;
    #pragma unroll
    for (int i = 0; i < 8; ++i) {                 // lane-contiguous: coalesced
        int k = q + i * 16;
        float4 x = iv[k], y = tv[k], w = cv[k];
        sii += x.x*x.x + x.y*x.y + x.z*x.z + x.w*x.w;
        stt += y.x*y.x + y.y*y.y + y.z*y.z + y.w*y.w;
        scc += w.x*w.x + w.y*w.y + w.z*w.z + w.w*w.w;
        sit += x.x*y.x + x.y*y.y + x.z*y.z + x.w*y.w;
        sic += x.x*w.x + x.y*w.y + x.z*w.z + x.w*w.w;
    }
    #pragma unroll
    for (int off = 1; off < 16; off <<= 1) {
        sii += __shfl_xor(sii, off); stt += __shfl_xor(stt, off);
        scc += __shfl_xor(scc, off); sit += __shfl_xor(sit, off);
        sic += __shfl_xor(sic, off);
    }
    if (q == 0) {
        float rnI = 1.0f / (sqrtf(sii) + 1e-8f);
        float rnT = 1.0f / (sqrtf(stt) + 1e-8f);
        float rnC = 1.0f / (sqrtf(scc) + 1e-8f);
        float ds = sit * rnI * rnT;
        float dc = sic * rnI * rnC;
        float m  = margin[r];
        float mcr = flagp[0] ? (fminf(fabsf(dc) / fabsf(ds), 1.0f) + 1.0f) * m * 0.5f
                             : m * 0.5f;
        rnImg[r] = rnI; rnTxt[r] = rnT; rnCr[r] = rnC;
        dgSim[r] = ds;  dgCr[r]  = dc;  mgCr[r] = mcr;
    }
}

__device__ inline void pass_arrays(int z,
        const float* img, const float* txt, const float* cr,
        const float* rnImg, const float* rnTxt, const float* rnCr,
        const float* dgSim, const float* dgCr,
        const float* margin, const float* mgCr,
        const float*& A, const float*& B, const float*& rnA, const float*& rnB,
        const float*& dgA, const float*& mgA) {
    if (z == 0)      { A = img; B = txt; rnA = rnImg; rnB = rnTxt; dgA = dgSim; mgA = margin; }
    else if (z == 1) { A = txt; B = img; rnA = rnTxt; rnB = rnImg; dgA = dgSim; mgA = margin; }
    else if (z == 2) { A = img; B = cr;  rnA = rnImg; rnB = rnCr;  dgA = dgCr;  mgA = mgCr;   }
    else             { A = cr;  B = img; rnA = rnCr;  rnB = rnImg; dgA = dgCr;  mgA = mgCr;   }
}

// ---------------------------------------------------------------------------
// band (R13): 64 anchors x 128 cols x K=512, acc[4][8].
// vs R12's 64x64 acc[4][4]: 3 LDS b128-reads per 32 FMA (was 2 per 16) —
// 25% fewer reads/FMA on the bound LDS pipe — and halves the straggler
// population (survival 1/65 -> 1/129), shrinking wina/tail.
// B-stores 2-way aliased (free); B-reads contiguous b128; A-read broadcast.
// ---------------------------------------------------------------------------
__global__ __launch_bounds__(256) void band_k(
        const float* __restrict__ img, const float* __restrict__ txt,
        const float* __restrict__ cr, const int* __restrict__ labels,
        const int* __restrict__ flagp, const float* __restrict__ margin,
        const float* __restrict__ betap,
        const float* rnImg, const float* rnTxt, const float* rnCr,
        const float* dgSim, const float* dgCr, const float* mgCr,
        int* stragCnt, int* stragList, float* out) {
    __shared__ __align__(16) float As[16][68];
    __shared__ __align__(16) float Bs[16][132];
    __shared__ float aRn[64], aDg[64], aMg[64], colRn[BANDW];
    __shared__ int   aLab[64], colLab[BANDW], resIdx[64];
    __shared__ float blockAcc;

    const int tid = threadIdx.x, z = blockIdx.y, a0 = blockIdx.x * 64;
    const int flag = flagp[0];
    const float *A, *B, *rnA, *rnB, *dgA, *mgA;
    pass_arrays(z, img, txt, cr, rnImg, rnTxt, rnCr, dgSim, dgCr, margin, mgCr,
                A, B, rnA, rnB, dgA, mgA);

    if (tid < 64) {
        int a = a0 + tid;
        float mg = mgA[a];
        aRn[tid] = rnA[a]; aDg[tid] = dgA[a]; aMg[tid] = mg;
        aLab[tid] = labels[a];
        resIdx[tid] = (flag && mg < 0.16f) ? -1 : INT_MAX;
    }
    if (tid < BANDW) { colRn[tid] = rnB[tid]; colLab[tid] = labels[tid]; }
    if (tid == 0) blockAcc = 0.0f;

    const int ty4  = (tid >> 4) * 4, tx8 = (tid & 15) * 8;
    const int lrow = tid >> 2,  lk4 = (tid & 3) * 4;     // A staging
    const int rowB = tid >> 1,  k8  = (tid & 1) * 8;     // B staging

    float acc[4][8];
    #pragma unroll
    for (int i = 0; i < 4; ++i)
        #pragma unroll
        for (int j = 0; j < 8; ++j) acc[i][j] = 0.0f;

    // software-pipelined staging: prefetch next kc while computing current
    float4 va  = *(const float4*)(A + (size_t)(a0 + lrow) * ND + lk4);
    float4 vb0 = *(const float4*)(B + (size_t)rowB * ND + k8);
    float4 vb1 = *(const float4*)(B + (size_t)rowB * ND + k8 + 4);
    for (int kc = 0; kc < ND; kc += 16) {
        __syncthreads();                       // prior compute done
        As[lk4 + 0][lrow] = va.x; As[lk4 + 1][lrow] = va.y;
        As[lk4 + 2][lrow] = va.z; As[lk4 + 3][lrow] = va.w;
        Bs[k8 + 0][rowB] = vb0.x; Bs[k8 + 1][rowB] = vb0.y;
        Bs[k8 + 2][rowB] = vb0.z; Bs[k8 + 3][rowB] = vb0.w;
        Bs[k8 + 4][rowB] = vb1.x; Bs[k8 + 5][rowB] = vb1.y;
        Bs[k8 + 6][rowB] = vb1.z; Bs[k8 + 7][rowB] = vb1.w;
        if (kc + 16 < ND) {
            va  = *(const float4*)(A + (size_t)(a0 + lrow) * ND + kc + 16 + lk4);
            vb0 = *(const float4*)(B + (size_t)rowB * ND + kc + 16 + k8);
            vb1 = *(const float4*)(B + (size_t)rowB * ND + kc + 16 + k8 + 4);
        }
        __syncthreads();
        #pragma unroll
        for (int k = 0; k < 16; ++k) {
            float4 av = *(const float4*)&As[k][ty4];
            float4 b0 = *(const float4*)&Bs[k][tx8];
            float4 b1 = *(const float4*)&Bs[k][tx8 + 4];
            float ar[4] = {av.x, av.y, av.z, av.w};
            float br[8] = {b0.x, b0.y, b0.z, b0.w, b1.x, b1.y, b1.z, b1.w};
            #pragma unroll
            for (int i = 0; i < 4; ++i)
                #pragma unroll
                for (int j = 0; j < 8; ++j)
                    acc[i][j] = fmaf(ar[i], br[j], acc[i][j]);
        }
    }
    __syncthreads();

    // predicate pass: first valid (min col) via atomicMin
    #pragma unroll
    for (int i = 0; i < 4; ++i) {
        int r = ty4 + i;
        float mgv = aMg[r];
        if (flag && mgv < 0.16f) continue;     // pre-resolved: contributes 0
        float dg = aDg[r], rna = aRn[r];
        int la = aLab[r];
        #pragma unroll
        for (int j = 0; j < 8; ++j) {
            int c = tx8 + j;
            if (colLab[c] == la) continue;
            float lm = acc[i][j] * rna * colRn[c] - dg + mgv;
            if (lm > 0.0f && lm < mgv) atomicMin(&resIdx[r], c);
        }
    }
    __syncthreads();

    // winner pass: unique owner thread of the winning column adds lm
    #pragma unroll
    for (int i = 0; i < 4; ++i) {
        int r = ty4 + i;
        int w = resIdx[r];
        if (w < 0 || w == INT_MAX) continue;
        int c = w - tx8;
        if (c < 0 || c > 7) continue;
        float lm = acc[i][c] * aRn[r] * colRn[w] - aDg[r] + aMg[r];
        atomicAdd(&blockAcc, lm);
    }
    __syncthreads();

    if (tid < 64 && resIdx[tid] == INT_MAX) {  // unresolved -> global straggler
        int pos = atomicAdd(&stragCnt[z], 1);
        stragList[z * NB + pos] = a0 + tid;
    }
    if (tid == 0 && blockAcc != 0.0f) {
        float scale = (z >= 2) ? betap[0] : 1.0f;
        atomicAdd(out, blockAcc * scale);
    }
}

// ---------------------------------------------------------------------------
// wina: gathered 64-straggler tiles x 32-col chunks over [WSTART,WCOLS).
// Grid (WCHUNKS*WTILES, 4) = 512 blocks; inactive tiles exit immediately.
// Candidates stored as packed (col, lm) u64 — enables recompute-free final.
// ---------------------------------------------------------------------------
__global__ __launch_bounds__(256) void wina_k(
        const float* __restrict__ img, const float* __restrict__ txt,
        const float* __restrict__ cr, const int* __restrict__ labels,
        const float* __restrict__ margin,
        const float* rnImg, const float* rnTxt, const float* rnCr,
        const float* dgSim, const float* dgCr, const float* mgCr,
        const int* stragCnt, const int* stragList,
        unsigned long long* negIdx64) {
    __shared__ __align__(16) float As[16][68];
    __shared__ __align__(16) float Bs[16][36];
    __shared__ float aRn[64], aDg[64], aMg[64], colRn[32];
    __shared__ int   aId[64], aRow[64], aLab[64], colLab[32];

    const int tid = threadIdx.x, z = blockIdx.y;
    const int chunk = blockIdx.x & (WCHUNKS - 1);
    const int t     = blockIdx.x / WCHUNKS;
    int cnt = stragCnt[z];
    if (cnt <= 0) return;
    cnt = min(cnt, NB);                        // replay-safe clamp
    if (t * 64 >= cnt) return;                 // uniform: no anchors here
    const int c0 = WSTART + chunk * 32;

    const float *A, *B, *rnA, *rnB, *dgA, *mgA;
    pass_arrays(z, img, txt, cr, rnImg, rnTxt, rnCr, dgSim, dgCr, margin, mgCr,
                A, B, rnA, rnB, dgA, mgA);

    if (tid < 64) {
        int s = t * 64 + tid;
        int a = (s < cnt) ? stragList[z * NB + s] : -1;
        if ((unsigned)a >= NB) a = -1;         // replay-safe bound
        int ar = (a >= 0) ? a : 0;             // dummy row for padding lanes
        aId[tid] = a; aRow[tid] = ar;
        aRn[tid] = rnA[ar]; aDg[tid] = dgA[ar]; aMg[tid] = mgA[ar];
        aLab[tid] = labels[ar];
    }
    if (tid < 32) { colRn[tid] = rnB[c0 + tid]; colLab[tid] = labels[c0 + tid]; }
    __syncthreads();

    const int ty4  = (tid >> 4) * 4, tx2 = (tid & 15) * 2;
    const int lrow = tid >> 2,  lk4 = (tid & 3) * 4;
    const int arow = aRow[lrow];
    const bool doB = tid < 128;                // 32 B-rows x 4 f4-chunks

    float acc[4][2];
    #pragma unroll
    for (int i = 0; i < 4; ++i) { acc[i][0] = 0.0f; acc[i][1] = 0.0f; }

    float4 va = *(const float4*)(A + (size_t)arow * ND + lk4);
    float4 vb;
    if (doB) vb = *(const float4*)(B + (size_t)(c0 + lrow) * ND + lk4);
    for (int kc = 0; kc < ND; kc += 16) {
        __syncthreads();                       // prior compute done
        As[lk4 + 0][lrow] = va.x; As[lk4 + 1][lrow] = va.y;
        As[lk4 + 2][lrow] = va.z; As[lk4 + 3][lrow] = va.w;
        if (doB) {
            Bs[lk4 + 0][lrow] = vb.x; Bs[lk4 + 1][lrow] = vb.y;
            Bs[lk4 + 2][lrow] = vb.z; Bs[lk4 + 3][lrow] = vb.w;
        }
        if (kc + 16 < ND) {
            va = *(const float4*)(A + (size_t)arow * ND + kc + 16 + lk4);
            if (doB) vb = *(const float4*)(B + (size_t)(c0 + lrow) * ND + kc + 16 + lk4);
        }
        __syncthreads();
        #pragma unroll
        for (int k = 0; k < 16; ++k) {
            float4 av = *(const float4*)&As[k][ty4];
            float2 bv = *(const float2*)&Bs[k][tx2];
            float ar[4] = {av.x, av.y, av.z, av.w};
            #pragma unroll
            for (int i = 0; i < 4; ++i) {
                acc[i][0] = fmaf(ar[i], bv.x, acc[i][0]);
                acc[i][1] = fmaf(ar[i], bv.y, acc[i][1]);
            }
        }
    }
    __syncthreads();

    #pragma unroll
    for (int i = 0; i < 4; ++i) {
        int r = ty4 + i;
        int a = aId[r];
        if (a < 0) continue;
        float dg = aDg[r], mgv = aMg[r], rna = aRn[r];
        int la = aLab[r];
        #pragma unroll
        for (int j = 0; j < 2; ++j) {
            int c = tx2 + j;
            if (colLab[c] == la) continue;
            float lm = acc[i][j] * rna * colRn[c] - dg + mgv;
            if (lm > 0.0f && lm < mgv)
                atomicMin(&negIdx64[z * NB + a], pack_cand(c0 + c, lm));
        }
    }
}

__device__ inline float dot8(const float4& a0, const float4& a1,
                             const float4& b0, const float4& b1) {
    return a0.x*b0.x + a0.y*b0.y + a0.z*b0.z + a0.w*b0.w
         + a1.x*b1.x + a1.y*b1.y + a1.z*b1.z + a1.w*b1.w;
}

// ---------------------------------------------------------------------------
// tail: survivors of wina swept over 32-col chunks (252x4 blocks ~4/CU) —
// the R5-proven structure. gn-bounded survivor loop; A-stage only gn rows;
// wina-covered range skipped. Packed (col,lm) stores.
// ---------------------------------------------------------------------------
__global__ __launch_bounds__(256) void tail_k(
        const float* __restrict__ img, const float* __restrict__ txt,
        const float* __restrict__ cr, const int* __restrict__ labels,
        const float* __restrict__ margin,
        const float* rnImg, const float* rnTxt, const float* rnCr,
        const float* dgSim, const float* dgCr, const float* mgCr,
        const int* stragCnt, const int* stragList,
        unsigned long long* negIdx64) {
    __shared__ __align__(16) float Aload[8][ND];   // 16 KB
    __shared__ float sRn[8], sDg[8], sMg[8];
    __shared__ int   sLab[8], sAid[8];
    __shared__ float colRn_s[32];
    __shared__ int   colLab_s[32];
    __shared__ int   sSurv[256];
    __shared__ int   sNa;

    const int tid = threadIdx.x, z = blockIdx.y;
    const int c0 = WSTART + blockIdx.x * 32;
    int cnt = stragCnt[z];
    if (cnt <= 0) return;
    cnt = min(cnt, NB);                        // replay-safe clamp
    // wina fully covered [WSTART,WCOLS) unless its capacity overflowed
    if (cnt <= WCAP && c0 < WCOLS) return;

    const float *A, *B, *rnA, *rnB, *dgA, *mgA;
    pass_arrays(z, img, txt, cr, rnImg, rnTxt, rnCr, dgSim, dgCr, margin, mgCr,
                A, B, rnA, rnB, dgA, mgA);

    // survivor compaction (order irrelevant: result is a global min)
    if (tid == 0) sNa = 0;
    __syncthreads();
    for (int s = tid; s < cnt; s += 256) {
        int a = stragList[z * NB + s];
        if ((unsigned)a < NB && negIdx64[z * NB + a] == PK_NONE) {
            int p = atomicAdd(&sNa, 1);
            if (p < 256) sSurv[p] = a;
        }
    }
    __syncthreads();
    const int na = min(sNa, 256);
    if (na == 0) return;

    if (tid < 32) { colRn_s[tid] = rnB[c0 + tid]; colLab_s[tid] = labels[c0 + tid]; }

    const int wv = tid >> 6, lane = tid & 63;

    for (int g0 = 0; g0 < na; g0 += 8) {
        const int gn = min(8, na - g0);
        __syncthreads();                       // protect Aload/params reuse
        if (tid < 8) {
            int s = g0 + ((tid < gn) ? tid : 0);
            int a = sSurv[s];
            sAid[tid] = (tid < gn) ? a : -1;
            sRn[tid] = rnA[a]; sDg[tid] = dgA[a]; sMg[tid] = mgA[a];
            sLab[tid] = labels[a];
        }
        #pragma unroll
        for (int m = 0; m < 4; ++m) {          // stage gn survivor rows
            int idx = tid + m * 256;
            int row = idx >> 7, f4 = idx & 127;
            if (row < gn) {
                int a = sSurv[g0 + row];
                *(float4*)&Aload[row][f4 * 4] =
                    *(const float4*)(A + (size_t)a * ND + f4 * 4);
            }
        }
        __syncthreads();

        // each wave: 8 cols, in batches of 4 (B loads shared across survivors)
        #pragma unroll
        for (int cb = 0; cb < 2; ++cb) {
            const int cc0 = wv * 8 + cb * 4;
            float4 b0[4], b1[4];
            #pragma unroll
            for (int q = 0; q < 4; ++q) {
                const float4* Bv = (const float4*)(B + (size_t)(c0 + cc0 + q) * ND);
                b0[q] = Bv[lane]; b1[q] = Bv[lane + 64];
            }
            for (int s = 0; s < gn; ++s) {     // gn-bounded: no padding work
                float4 a0v = *(const float4*)&Aload[s][lane * 4];
                float4 a1v = *(const float4*)&Aload[s][(lane + 64) * 4];
                float d0 = dot8(a0v, a1v, b0[0], b1[0]);
                float d1 = dot8(a0v, a1v, b0[1], b1[1]);
                float d2 = dot8(a0v, a1v, b0[2], b1[2]);
                float d3 = dot8(a0v, a1v, b0[3], b1[3]);
                #pragma unroll
                for (int off = 1; off < 64; off <<= 1) {
                    d0 += __shfl_xor(d0, off); d1 += __shfl_xor(d1, off);
                    d2 += __shfl_xor(d2, off); d3 += __shfl_xor(d3, off);
                }
                if (lane == 0) {
                    int aid = sAid[s];
                    float rn = sRn[s], dg = sDg[s], mg = sMg[s];
                    int lb = sLab[s];
                    float dv[4] = {d0, d1, d2, d3};
                    #pragma unroll
                    for (int q = 0; q < 4; ++q) {
                        int cc = cc0 + q;
                        if (colLab_s[cc] != lb) {
                            float lm = dv[q] * rn * colRn_s[cc] - dg + mg;
                            if (lm > 0.0f && lm < mg)
                                atomicMin(&negIdx64[z * NB + aid],
                                          pack_cand(c0 + cc, lm));
                        }
                    }
                }
            }
        }
    }
}

// ---------------------------------------------------------------------------
// final: sum stored (col,lm) payloads per straggler — NO dot recompute
// (R10-measured win). Cross-kernel stream ordering makes plain loads coherent.
// ---------------------------------------------------------------------------
__global__ __launch_bounds__(256) void final_k(
        const float* __restrict__ betap,
        const int* stragCnt, const int* stragList,
        const unsigned long long* negIdx64, float* out) {
    __shared__ float s4[4];
    const int tid = threadIdx.x, z = blockIdx.y;
    int cnt = stragCnt[z];
    cnt = (cnt < 0) ? 0 : min(cnt, NB);        // replay-safe clamp
    int t = blockIdx.x * 256 + tid;
    float contrib = 0.0f;
    if (t < cnt) {
        int a = stragList[z * NB + t];
        if ((unsigned)a < NB) {
            unsigned long long pk = negIdx64[z * NB + a];
            if (pk != PK_NONE) {
                unsigned col = (unsigned)(pk >> 32);
                if (col < NB) {                // replay-safe sanity
                    float lm = __uint_as_float((unsigned)(pk & 0xFFFFFFFFu));
                    contrib = fmaxf(lm, 0.0f); // 0<lm<mg => relu identity
                }
            }
        }
    }
    #pragma unroll
    for (int off = 32; off; off >>= 1) contrib += __shfl_xor(contrib, off);
    if ((tid & 63) == 0) s4[tid >> 6] = contrib;
    __syncthreads();
    if (tid == 0) {
        float sum = s4[0] + s4[1] + s4[2] + s4[3];
        if (sum != 0.0f) atomicAdd(out, sum * ((z >= 2) ? betap[0] : 1.0f));
    }
}

// ===========================================================================
// Fallback path (no workspace) — the proven round-3 single-kernel version.
// ===========================================================================

__global__ __launch_bounds__(256) void zero_k(float* out, int n) {
    int g = blockIdx.x * 256 + threadIdx.x;
    if (g < n) out[g] = 0.0f;
}

template <int U>
__device__ void stragScan(const float* __restrict__ A, const float* __restrict__ B,
                          const int* __restrict__ labels, int a0, int u, int scol,
                          const int* sList, int g0,
                          const float* aRn, const float* aDg, const float* aMg,
                          const int* aLab, int* sMin8, int* doneMask,
                          float* blockAcc) {
    const int tid = threadIdx.x;
    float rn_s[U], dg_s[U], mg_s[U];
    int lab_s[U];
    const float4* Av[U];
    #pragma unroll
    for (int s = 0; s < U; ++s) {
        int slot = sList[g0 + (s < u ? s : 0)];
        rn_s[s] = aRn[slot]; dg_s[s] = aDg[slot]; mg_s[s] = aMg[slot];
        lab_s[s] = aLab[slot];
        Av[s] = (const float4*)(A + (size_t)(a0 + slot) * ND);
    }
    if (tid < U) sMin8[tid] = INT_MAX;
    if (tid == 0) *doneMask = 0;
    __syncthreads();
    for (int jb = scol; jb < NB; jb += 256) {
        int j = jb + tid;
        bool jv = (j < NB);
        int mask = *doneMask;
        float dot[U];
        #pragma unroll
        for (int s = 0; s < U; ++s) dot[s] = 0.0f;
        float ssq = 0.0f;
        if (jv) {
            const float4* Bv = (const float4*)(B + (size_t)j * ND);
            #pragma unroll 4
            for (int k4 = 0; k4 < ND / 4; ++k4) {
                float4 b = Bv[k4];
                ssq += b.x*b.x + b.y*b.y + b.z*b.z + b.w*b.w;
                #pragma unroll
                for (int s = 0; s < U; ++s) {
                    float4 a = Av[s][k4];
                    dot[s] += a.x*b.x + a.y*b.y + a.z*b.z + a.w*b.w;
                }
            }
        }
        float rnb = 1.0f / (sqrtf(ssq) + 1e-8f);
        int lj = jv ? labels[j] : -1;
        float lmv[U];
        #pragma unroll
        for (int s = 0; s < U; ++s) {
            lmv[s] = dot[s] * rn_s[s] * rnb - dg_s[s] + mg_s[s];
            if (jv && s < u && !((mask >> s) & 1) && lj != lab_s[s] &&
                lmv[s] > 0.0f && lmv[s] < mg_s[s])
                atomicMin(&sMin8[s], j);
        }
        __syncthreads();
        #pragma unroll
        for (int s = 0; s < U; ++s)
            if (jv && s < u && !((mask >> s) & 1) && sMin8[s] == j)
                atomicAdd(blockAcc, lmv[s]);
        __syncthreads();
        if (tid == 0) {
            int m2 = 0;
            for (int s = 0; s < u; ++s)
                if (sMin8[s] != INT_MAX) m2 |= (1 << s);
            *doneMask = m2;
        }
        __syncthreads();
        if (*doneMask == (1 << u) - 1) break;
    }
}

__global__ __launch_bounds__(256) void mine_k(const float* __restrict__ img,
                                              const float* __restrict__ txt,
                                              const float* __restrict__ cr,
                                              const int*   __restrict__ labels,
                                              const int*   __restrict__ flagp,
                                              const float* __restrict__ margin,
                                              const float* __restrict__ betap,
                                              float* __restrict__ out) {
    __shared__ __align__(16) float As[16][64];
    __shared__ __align__(16) float Bs[16][64];
    __shared__ float aRn[64], aDg[64], aMg[64];
    __shared__ int   aLab[64];
    __shared__ float colRn[64];
    __shared__ int   colLab[64];
    __shared__ int   resIdx[64], prevIdx[64];
    __shared__ int   cnt;
    __shared__ float blockAcc;
    __shared__ int   sList[64];
    __shared__ int   sCnt;
    __shared__ int   sMin8[8];
    __shared__ int   doneMask;

    const int tid  = threadIdx.x;
    const int z    = blockIdx.y;
    const int a0   = blockIdx.x * 64;
    const int flag = flagp[0];
    const float* A = (z == 1) ? txt : (z == 3) ? cr : img;
    const float* B = (z == 0) ? txt : (z == 2) ? cr : img;
    {
        int ar = tid >> 2, q = tid & 3;
        int a  = a0 + ar;
        const float4* iv = (const float4*)(img + (size_t)a * ND) + q * 32;
        const float4* tv = (const float4*)(txt + (size_t)a * ND) + q * 32;
        const float4* cv = (const float4*)(cr  + (size_t)a * ND) + q * 32;
        float sii = 0, stt = 0, scc = 0, sit = 0, sic = 0;
        #pragma unroll 4
        for (int i = 0; i < 32; ++i) {
            float4 x = iv[i], y = tv[i], w = cv[i];
            sii += x.x*x.x + x.y*x.y + x.z*x.z + x.w*x.w;
            stt += y.x*y.x + y.y*y.y + y.z*y.z + y.w*y.w;
            scc += w.x*w.x + w.y*w.y + w.z*w.z + w.w*w.w;
            sit += x.x*y.x + x.y*y.y + x.z*y.z + x.w*y.w;
            sic += x.x*w.x + x.y*w.y + x.z*w.z + x.w*w.w;
        }
        sii += __shfl_xor(sii, 1); sii += __shfl_xor(sii, 2);
        stt += __shfl_xor(stt, 1); stt += __shfl_xor(stt, 2);
        sit += __shfl_xor(sit, 1); sit += __shfl_xor(sit, 2);
        scc += __shfl_xor(scc, 1); scc += __shfl_xor(scc, 2);
        sic += __shfl_xor(sic, 1); sic += __shfl_xor(sic, 2);
        if (q == 0) {
            float rnI = 1.0f / (sqrtf(sii) + 1e-8f);
            float rnT = 1.0f / (sqrtf(stt) + 1e-8f);
            float ds  = sit * rnI * rnT;
            float m   = margin[a];
            float mg, rna, dgv;
            if (z >= 2) {
                float rnC = 1.0f / (sqrtf(scc) + 1e-8f);
                float dc  = sic * rnI * rnC;
                mg = flag ? (fminf(fabsf(dc) / fabsf(ds), 1.0f) + 1.0f) * m * 0.5f
                          : m * 0.5f;
                dgv = dc; rna = (z == 3) ? rnC : rnI;
            } else {
                mg = m; dgv = ds; rna = (z == 1) ? rnT : rnI;
            }
            aRn[ar] = rna; aDg[ar] = dgv; aMg[ar] = mg; aLab[ar] = labels[a];
            resIdx[ar] = (flag && mg < 0.16f) ? -1 : INT_MAX;
        }
        if (tid == 0) blockAcc = 0.0f;
    }
    __syncthreads();
    const int ty4  = (tid >> 4) * 4, tx4 = (tid & 15) * 4;
    const int lrow = tid >> 2,  lk4 = (tid & 3) * 4;
    int bandCols = 0, unresolved = 64;
    for (int jc = 0; jc < 2; ++jc) {
        int j0 = jc * 64;
        float acc[4][4];
        #pragma unroll
        for (int i = 0; i < 4; ++i)
            #pragma unroll
            for (int j = 0; j < 4; ++j) acc[i][j] = 0.0f;
        float bssq = 0.0f;
        for (int kc = 0; kc < ND; kc += 16) {
            __syncthreads();
            float4 va = *(const float4*)(A + (size_t)(a0 + lrow) * ND + kc + lk4);
            float4 vb = *(const float4*)(B + (size_t)(j0 + lrow) * ND + kc + lk4);
            As[lk4 + 0][lrow] = va.x; As[lk4 + 1][lrow] = va.y;
            As[lk4 + 2][lrow] = va.z; As[lk4 + 3][lrow] = va.w;
            Bs[lk4 + 0][lrow] = vb.x; Bs[lk4 + 1][lrow] = vb.y;
            Bs[lk4 + 2][lrow] = vb.z; Bs[lk4 + 3][lrow] = vb.w;
            bssq += vb.x*vb.x + vb.y*vb.y + vb.z*vb.z + vb.w*vb.w;
            __syncthreads();
            #pragma unroll
            for (int k = 0; k < 16; ++k) {
                float4 av = *(const float4*)&As[k][ty4];
                float4 bv = *(const float4*)&Bs[k][tx4];
                float ar[4] = {av.x, av.y, av.z, av.w};
                float br[4] = {bv.x, bv.y, bv.z, bv.w};
                #pragma unroll
                for (int i = 0; i < 4; ++i)
                    #pragma unroll
                    for (int j = 0; j < 4; ++j)
                        acc[i][j] = fmaf(ar[i], br[j], acc[i][j]);
            }
        }
        bssq += __shfl_xor(bssq, 1); bssq += __shfl_xor(bssq, 2);
        __syncthreads();
        if ((tid & 3) == 0) {
            colRn[lrow]  = 1.0f / (sqrtf(bssq) + 1e-8f);
            colLab[lrow] = labels[j0 + lrow];
        }
        if (tid < 64) prevIdx[tid] = resIdx[tid];
        __syncthreads();
        #pragma unroll
        for (int i = 0; i < 4; ++i) {
            int r = ty4 + i;
            if (prevIdx[r] != INT_MAX) continue;
            float dg = aDg[r], mgv = aMg[r], rna = aRn[r];
            int la = aLab[r];
            #pragma unroll
            for (int j = 0; j < 4; ++j) {
                int c = tx4 + j;
                if (colLab[c] == la) continue;
                float v  = acc[i][j] * rna * colRn[c];
                float lm = v - dg + mgv;
                if (lm > 0.0f && lm < mgv) atomicMin(&resIdx[r], j0 + c);
            }
        }
        __syncthreads();
        #pragma unroll
        for (int i = 0; i < 4; ++i) {
            int r = ty4 + i;
            if (prevIdx[r] != INT_MAX) continue;
            int w = resIdx[r];
            if (w == INT_MAX) continue;
            int c = w - j0 - tx4;
            if (c < 0 || c > 3) continue;
            float v  = acc[i][c] * aRn[r] * colRn[tx4 + c];
            float lm = v - aDg[r] + aMg[r];
            atomicAdd(&blockAcc, lm);
        }
        __syncthreads();
        if (tid == 0) cnt = 0;
        __syncthreads();
        if (tid < 64 && resIdx[tid] == INT_MAX) atomicAdd(&cnt, 1);
        __syncthreads();
        unresolved = cnt;
        bandCols = j0 + 64;
        __syncthreads();
        if (unresolved <= 8) break;
    }
    if (unresolved > 0) {
        if (tid == 0) sCnt = 0;
        __syncthreads();
        if (tid < 64 && resIdx[tid] == INT_MAX) {
            int pos = atomicAdd(&sCnt, 1);
            sList[pos] = tid;
        }
        __syncthreads();
        int total = sCnt;
        for (int g0 = 0; g0 < total; g0 += 8) {
            int u = min(8, total - g0);
            if (u == 1)      stragScan<1>(A, B, labels, a0, u, bandCols, sList, g0, aRn, aDg, aMg, aLab, sMin8, &doneMask, &blockAcc);
            else if (u == 2) stragScan<2>(A, B, labels, a0, u, bandCols, sList, g0, aRn, aDg, aMg, aLab, sMin8, &doneMask, &blockAcc);
            else if (u <= 4) stragScan<4>(A, B, labels, a0, u, bandCols, sList, g0, aRn, aDg, aMg, aLab, sMin8, &doneMask, &blockAcc);
            else             stragScan<8>(A, B, labels, a0, u, bandCols, sList, g0, aRn, aDg, aMg, aLab, sMin8, &doneMask, &blockAcc);
            __syncthreads();
        }
    }
    if (tid == 0 && blockAcc != 0.0f) {
        float scale = (z >= 2) ? betap[0] : 1.0f;
        atomicAdd(out, blockAcc * scale);
    }
}

// ===========================================================================

extern "C" void kernel_launch(void* const* d_in, const int* in_sizes, int n_in,
                              void* d_out, int out_size, void* d_ws, size_t ws_size,
                              hipStream_t stream) {
    const float* img    = (const float*)d_in[0];
    const float* txt    = (const float*)d_in[1];
    const float* cr     = (const float*)d_in[2];
    const int*   labels = (const int*)  d_in[3];
    const int*   flagp  = (const int*)  d_in[4];
    const float* marg   = (const float*)d_in[5];
    const float* betap  = (const float*)d_in[6];
    float* out = (float*)d_out;
    (void)in_sizes; (void)n_in;

    const size_t REQ = (size_t)(6 * NB) * 4 + (size_t)(4 * NB) * 8 + 64 +
                       (size_t)(4 * NB) * 4;
    if (ws_size >= REQ) {
        float* wf = (float*)d_ws;
        float* rnImg = wf + 0 * NB;
        float* rnTxt = wf + 1 * NB;
        float* rnCr  = wf + 2 * NB;
        float* dgSim = wf + 3 * NB;
        float* dgCr  = wf + 4 * NB;
        float* mgCr  = wf + 5 * NB;
        unsigned long long* negIdx64 = (unsigned long long*)(wf + 6 * NB);
        int* stragCnt  = (int*)(negIdx64 + 4 * NB);
        int* stragList = stragCnt + 16;

        stats_k<<<dim3(NB / 16),              dim3(256), 0, stream>>>(
            img, txt, cr, marg, flagp,
            rnImg, rnTxt, rnCr, dgSim, dgCr, mgCr, negIdx64, stragCnt, out);
        band_k <<<dim3(NB / 64, 4),           dim3(256), 0, stream>>>(
            img, txt, cr, labels, flagp, marg, betap,
            rnImg, rnTxt, rnCr, dgSim, dgCr, mgCr, stragCnt, stragList, out);
        wina_k <<<dim3(WCHUNKS * WTILES, 4),  dim3(256), 0, stream>>>(
            img, txt, cr, labels, marg,
            rnImg, rnTxt, rnCr, dgSim, dgCr, mgCr,
            stragCnt, stragList, negIdx64);
        tail_k <<<dim3(TCHUNKS, 4),           dim3(256), 0, stream>>>(
            img, txt, cr, labels, marg,
            rnImg, rnTxt, rnCr, dgSim, dgCr, mgCr,
            stragCnt, stragList, negIdx64);
        final_k<<<dim3(NB / 256, 4),          dim3(256), 0, stream>>>(
            betap, stragCnt, stragList, negIdx64, out);
    } else {
        zero_k<<<dim3((out_size + 255) / 256), dim3(256), 0, stream>>>(out, out_size);
        mine_k<<<dim3(NB / 64, 4), dim3(256), 0, stream>>>(img, txt, cr, labels,
                                                           flagp, marg, betap, out);
    }
}

// Round 14
// 217.665 us; speedup vs baseline: 1.0107x; 1.0107x over previous
//
#include <hip/hip_runtime.h>
#include <climits>

// Problem constants (fixed by the reference): B=8192 rows, D=512 features.
#define NB 8192
#define ND 512

// Band covers cols [0,BANDW); wina [WSTART, WCOLS); tail [WSTART, NB).
#define BANDW 128
#define WSTART BANDW                 // 128
#define WCHUNKS 32
#define WTILES 4
#define WCAP (WTILES * 64)           // 256 stragglers/z
#define WCOLS (WSTART + WCHUNKS * 32)  // 1152
#define TCHUNKS ((NB - WSTART) / 32)   // 252

#define PK_NONE (~0ULL)

// pack (col, lm) so u64 atomicMin selects min col; lm>0 => bits monotone.
__device__ inline unsigned long long pack_cand(int col, float lm) {
    return ((unsigned long long)(unsigned)col << 32) |
           (unsigned long long)__float_as_uint(lm);
}

// ===========================================================================
// Fast path: stats -> band -> wina -> tail -> final through d_ws.
// ws layout: floats rnImg rnTxt rnCr dgSim dgCr mgCr [6*NB];
//            u64 negIdx64 [4*NB]; int stragCnt [16]; int stragList [4*NB]
// ===========================================================================

// Per-row stats + workspace init. 16 threads/row, 16 rows/block, 512 blocks.
__global__ __launch_bounds__(256) void stats_k(
        const float* __restrict__ img, const float* __restrict__ txt,
        const float* __restrict__ cr, const float* __restrict__ margin,
        const int* __restrict__ flagp,
        float* rnImg, float* rnTxt, float* rnCr,
        float* dgSim, float* dgCr, float* mgCr,
        unsigned long long* negIdx64, int* stragCnt, float* out) {
    int tid = threadIdx.x, bid = blockIdx.x;
    int g = bid * 256 + tid;
    if (g < 4 * NB) negIdx64[g] = PK_NONE;
    if (bid == 0 && tid < 16) stragCnt[tid] = 0;
    if (bid == 0 && tid == 0) out[0] = 0.0f;

    int r = bid * 16 + (tid >> 4);
    int q = tid & 15;
    const float4* iv = (const float4*)(img + (size_t)r * ND);
    const float4* tv = (const float4*)(txt + (size_t)r * ND);
    const float4* cv = (const float4*)(cr  + (size_t)r * ND);
    float sii = 0, stt = 0, scc = 0, sit = 0, sic = 0;
    #pragma unroll
    for (int i = 0; i < 8; ++i) {                 // lane-contiguous: coalesced
        int k = q + i * 16;
        float4 x = iv[k], y = tv[k], w = cv[k];
        sii += x.x*x.x + x.y*x.y + x.z*x.z + x.w*x.w;
        stt += y.x*y.x + y.y*y.y + y.z*y.z + y.w*y.w;
        scc += w.x*w.x + w.y*w.y + w.z*w.z + w.w*w.w;
        sit += x.x*y.x + x.y*y.y + x.z*y.z + x.w*y.w;
        sic += x.x*w.x + x.y*w.y + x.z*w.z + x.w*w.w;
    }
    #pragma unroll
    for (int off = 1; off < 16; off <<= 1) {
        sii += __shfl_xor(sii, off); stt += __shfl_xor(stt, off);
        scc += __shfl_xor(scc, off); sit += __shfl_xor(sit, off);
        sic += __shfl_xor(sic, off);
    }
    if (q == 0) {
        float rnI = 1.0f / (sqrtf(sii) + 1e-8f);
        float rnT = 1.0f / (sqrtf(stt) + 1e-8f);
        float rnC = 1.0f / (sqrtf(scc) + 1e-8f);
        float ds = sit * rnI * rnT;
        float dc = sic * rnI * rnC;
        float m  = margin[r];
        float mcr = flagp[0] ? (fminf(fabsf(dc) / fabsf(ds), 1.0f) + 1.0f) * m * 0.5f
                             : m * 0.5f;
        rnImg[r] = rnI; rnTxt[r] = rnT; rnCr[r] = rnC;
        dgSim[r] = ds;  dgCr[r]  = dc;  mgCr[r] = mcr;
    }
}

__device__ inline void pass_arrays(int z,
        const float* img, const float* txt, const float* cr,
        const float* rnImg, const float* rnTxt, const float* rnCr,
        const float* dgSim, const float* dgCr,
        const float* margin, const float* mgCr,
        const float*& A, const float*& B, const float*& rnA, const float*& rnB,
        const float*& dgA, const float*& mgA) {
    if (z == 0)      { A = img; B = txt; rnA = rnImg; rnB = rnTxt; dgA = dgSim; mgA = margin; }
    else if (z == 1) { A = txt; B = img; rnA = rnTxt; rnB = rnImg; dgA = dgSim; mgA = margin; }
    else if (z == 2) { A = img; B = cr;  rnA = rnImg; rnB = rnCr;  dgA = dgCr;  mgA = mgCr;   }
    else             { A = cr;  B = img; rnA = rnCr;  rnB = rnImg; dgA = dgCr;  mgA = mgCr;   }
}

// ---------------------------------------------------------------------------
// band (R14): 64 anchors x 128 cols x K=512, acc[4][8].
// R13's 4-way LDS read conflict (tx8 = 32B-stride, SQ_LDS_BANK_CONFLICT
// 11.8M) fixed: 128 cols read as TWO 64-col halves at tx4 and tx4+64 —
// 16B-stride per read = the R12-proven 2-way-free pattern (+64 floats =
// 256B = bank-period multiple). 3 LDS reads per 32 FMA retained.
// ---------------------------------------------------------------------------
__global__ __launch_bounds__(256) void band_k(
        const float* __restrict__ img, const float* __restrict__ txt,
        const float* __restrict__ cr, const int* __restrict__ labels,
        const int* __restrict__ flagp, const float* __restrict__ margin,
        const float* __restrict__ betap,
        const float* rnImg, const float* rnTxt, const float* rnCr,
        const float* dgSim, const float* dgCr, const float* mgCr,
        int* stragCnt, int* stragList, float* out) {
    __shared__ __align__(16) float As[16][68];
    __shared__ __align__(16) float Bs[16][132];
    __shared__ float aRn[64], aDg[64], aMg[64], colRn[BANDW];
    __shared__ int   aLab[64], colLab[BANDW], resIdx[64];
    __shared__ float blockAcc;

    const int tid = threadIdx.x, z = blockIdx.y, a0 = blockIdx.x * 64;
    const int flag = flagp[0];
    const float *A, *B, *rnA, *rnB, *dgA, *mgA;
    pass_arrays(z, img, txt, cr, rnImg, rnTxt, rnCr, dgSim, dgCr, margin, mgCr,
                A, B, rnA, rnB, dgA, mgA);

    if (tid < 64) {
        int a = a0 + tid;
        float mg = mgA[a];
        aRn[tid] = rnA[a]; aDg[tid] = dgA[a]; aMg[tid] = mg;
        aLab[tid] = labels[a];
        resIdx[tid] = (flag && mg < 0.16f) ? -1 : INT_MAX;
    }
    if (tid < BANDW) { colRn[tid] = rnB[tid]; colLab[tid] = labels[tid]; }
    if (tid == 0) blockAcc = 0.0f;

    const int ty4  = (tid >> 4) * 4, tx4 = (tid & 15) * 4;
    const int lrow = tid >> 2,  lk4 = (tid & 3) * 4;     // A staging
    const int rowB = tid >> 1,  k8  = (tid & 1) * 8;     // B staging

    float acc[4][8];
    #pragma unroll
    for (int i = 0; i < 4; ++i)
        #pragma unroll
        for (int j = 0; j < 8; ++j) acc[i][j] = 0.0f;

    // software-pipelined staging: prefetch next kc while computing current
    float4 va  = *(const float4*)(A + (size_t)(a0 + lrow) * ND + lk4);
    float4 vb0 = *(const float4*)(B + (size_t)rowB * ND + k8);
    float4 vb1 = *(const float4*)(B + (size_t)rowB * ND + k8 + 4);
    for (int kc = 0; kc < ND; kc += 16) {
        __syncthreads();                       // prior compute done
        As[lk4 + 0][lrow] = va.x; As[lk4 + 1][lrow] = va.y;
        As[lk4 + 2][lrow] = va.z; As[lk4 + 3][lrow] = va.w;
        Bs[k8 + 0][rowB] = vb0.x; Bs[k8 + 1][rowB] = vb0.y;
        Bs[k8 + 2][rowB] = vb0.z; Bs[k8 + 3][rowB] = vb0.w;
        Bs[k8 + 4][rowB] = vb1.x; Bs[k8 + 5][rowB] = vb1.y;
        Bs[k8 + 6][rowB] = vb1.z; Bs[k8 + 7][rowB] = vb1.w;
        if (kc + 16 < ND) {
            va  = *(const float4*)(A + (size_t)(a0 + lrow) * ND + kc + 16 + lk4);
            vb0 = *(const float4*)(B + (size_t)rowB * ND + kc + 16 + k8);
            vb1 = *(const float4*)(B + (size_t)rowB * ND + kc + 16 + k8 + 4);
        }
        __syncthreads();
        #pragma unroll
        for (int k = 0; k < 16; ++k) {
            float4 av = *(const float4*)&As[k][ty4];
            float4 b0 = *(const float4*)&Bs[k][tx4];        // half 0: 2-way free
            float4 b1 = *(const float4*)&Bs[k][64 + tx4];   // half 1: 2-way free
            float ar[4] = {av.x, av.y, av.z, av.w};
            float br[8] = {b0.x, b0.y, b0.z, b0.w, b1.x, b1.y, b1.z, b1.w};
            #pragma unroll
            for (int i = 0; i < 4; ++i)
                #pragma unroll
                for (int j = 0; j < 8; ++j)
                    acc[i][j] = fmaf(ar[i], br[j], acc[i][j]);
        }
    }
    __syncthreads();

    // predicate pass: first valid (min col) via atomicMin
    // col mapping: j<4 -> tx4+j (half 0); j>=4 -> 64+tx4+(j-4) (half 1)
    #pragma unroll
    for (int i = 0; i < 4; ++i) {
        int r = ty4 + i;
        float mgv = aMg[r];
        if (flag && mgv < 0.16f) continue;     // pre-resolved: contributes 0
        float dg = aDg[r], rna = aRn[r];
        int la = aLab[r];
        #pragma unroll
        for (int j = 0; j < 8; ++j) {
            int c = (j < 4) ? (tx4 + j) : (64 + tx4 + (j - 4));
            if (colLab[c] == la) continue;
            float lm = acc[i][j] * rna * colRn[c] - dg + mgv;
            if (lm > 0.0f && lm < mgv) atomicMin(&resIdx[r], c);
        }
    }
    __syncthreads();

    // winner pass: unique owner thread of the winning column adds lm
    #pragma unroll
    for (int i = 0; i < 4; ++i) {
        int r = ty4 + i;
        int w = resIdx[r];
        if (w < 0 || w == INT_MAX) continue;
        int jj = -1;
        if (w < 64) {
            int c = w - tx4;
            if (c >= 0 && c <= 3) jj = c;
        } else {
            int c = w - 64 - tx4;
            if (c >= 0 && c <= 3) jj = 4 + c;
        }
        if (jj < 0) continue;
        float lm = acc[i][jj] * aRn[r] * colRn[w] - aDg[r] + aMg[r];
        atomicAdd(&blockAcc, lm);
    }
    __syncthreads();

    if (tid < 64 && resIdx[tid] == INT_MAX) {  // unresolved -> global straggler
        int pos = atomicAdd(&stragCnt[z], 1);
        stragList[z * NB + pos] = a0 + tid;
    }
    if (tid == 0 && blockAcc != 0.0f) {
        float scale = (z >= 2) ? betap[0] : 1.0f;
        atomicAdd(out, blockAcc * scale);
    }
}

// ---------------------------------------------------------------------------
// wina: gathered 64-straggler tiles x 32-col chunks over [WSTART,WCOLS).
// Grid (WCHUNKS*WTILES, 4) = 512 blocks; inactive tiles exit immediately.
// Candidates stored as packed (col, lm) u64 — enables recompute-free final.
// ---------------------------------------------------------------------------
__global__ __launch_bounds__(256) void wina_k(
        const float* __restrict__ img, const float* __restrict__ txt,
        const float* __restrict__ cr, const int* __restrict__ labels,
        const float* __restrict__ margin,
        const float* rnImg, const float* rnTxt, const float* rnCr,
        const float* dgSim, const float* dgCr, const float* mgCr,
        const int* stragCnt, const int* stragList,
        unsigned long long* negIdx64) {
    __shared__ __align__(16) float As[16][68];
    __shared__ __align__(16) float Bs[16][36];
    __shared__ float aRn[64], aDg[64], aMg[64], colRn[32];
    __shared__ int   aId[64], aRow[64], aLab[64], colLab[32];

    const int tid = threadIdx.x, z = blockIdx.y;
    const int chunk = blockIdx.x & (WCHUNKS - 1);
    const int t     = blockIdx.x / WCHUNKS;
    int cnt = stragCnt[z];
    if (cnt <= 0) return;
    cnt = min(cnt, NB);                        // replay-safe clamp
    if (t * 64 >= cnt) return;                 // uniform: no anchors here
    const int c0 = WSTART + chunk * 32;

    const float *A, *B, *rnA, *rnB, *dgA, *mgA;
    pass_arrays(z, img, txt, cr, rnImg, rnTxt, rnCr, dgSim, dgCr, margin, mgCr,
                A, B, rnA, rnB, dgA, mgA);

    if (tid < 64) {
        int s = t * 64 + tid;
        int a = (s < cnt) ? stragList[z * NB + s] : -1;
        if ((unsigned)a >= NB) a = -1;         // replay-safe bound
        int ar = (a >= 0) ? a : 0;             // dummy row for padding lanes
        aId[tid] = a; aRow[tid] = ar;
        aRn[tid] = rnA[ar]; aDg[tid] = dgA[ar]; aMg[tid] = mgA[ar];
        aLab[tid] = labels[ar];
    }
    if (tid < 32) { colRn[tid] = rnB[c0 + tid]; colLab[tid] = labels[c0 + tid]; }
    __syncthreads();

    const int ty4  = (tid >> 4) * 4, tx2 = (tid & 15) * 2;
    const int lrow = tid >> 2,  lk4 = (tid & 3) * 4;
    const int arow = aRow[lrow];
    const bool doB = tid < 128;                // 32 B-rows x 4 f4-chunks

    float acc[4][2];
    #pragma unroll
    for (int i = 0; i < 4; ++i) { acc[i][0] = 0.0f; acc[i][1] = 0.0f; }

    float4 va = *(const float4*)(A + (size_t)arow * ND + lk4);
    float4 vb;
    if (doB) vb = *(const float4*)(B + (size_t)(c0 + lrow) * ND + lk4);
    for (int kc = 0; kc < ND; kc += 16) {
        __syncthreads();                       // prior compute done
        As[lk4 + 0][lrow] = va.x; As[lk4 + 1][lrow] = va.y;
        As[lk4 + 2][lrow] = va.z; As[lk4 + 3][lrow] = va.w;
        if (doB) {
            Bs[lk4 + 0][lrow] = vb.x; Bs[lk4 + 1][lrow] = vb.y;
            Bs[lk4 + 2][lrow] = vb.z; Bs[lk4 + 3][lrow] = vb.w;
        }
        if (kc + 16 < ND) {
            va = *(const float4*)(A + (size_t)arow * ND + kc + 16 + lk4);
            if (doB) vb = *(const float4*)(B + (size_t)(c0 + lrow) * ND + kc + 16 + lk4);
        }
        __syncthreads();
        #pragma unroll
        for (int k = 0; k < 16; ++k) {
            float4 av = *(const float4*)&As[k][ty4];
            float2 bv = *(const float2*)&Bs[k][tx2];
            float ar[4] = {av.x, av.y, av.z, av.w};
            #pragma unroll
            for (int i = 0; i < 4; ++i) {
                acc[i][0] = fmaf(ar[i], bv.x, acc[i][0]);
                acc[i][1] = fmaf(ar[i], bv.y, acc[i][1]);
            }
        }
    }
    __syncthreads();

    #pragma unroll
    for (int i = 0; i < 4; ++i) {
        int r = ty4 + i;
        int a = aId[r];
        if (a < 0) continue;
        float dg = aDg[r], mgv = aMg[r], rna = aRn[r];
        int la = aLab[r];
        #pragma unroll
        for (int j = 0; j < 2; ++j) {
            int c = tx2 + j;
            if (colLab[c] == la) continue;
            float lm = acc[i][j] * rna * colRn[c] - dg + mgv;
            if (lm > 0.0f && lm < mgv)
                atomicMin(&negIdx64[z * NB + a], pack_cand(c0 + c, lm));
        }
    }
}

__device__ inline float dot8(const float4& a0, const float4& a1,
                             const float4& b0, const float4& b1) {
    return a0.x*b0.x + a0.y*b0.y + a0.z*b0.z + a0.w*b0.w
         + a1.x*b1.x + a1.y*b1.y + a1.z*b1.z + a1.w*b1.w;
}

// ---------------------------------------------------------------------------
// tail: survivors of wina swept over 32-col chunks (252x4 blocks ~4/CU) —
// the R5-proven structure. gn-bounded survivor loop; A-stage only gn rows;
// wina-covered range skipped. Packed (col,lm) stores.
// ---------------------------------------------------------------------------
__global__ __launch_bounds__(256) void tail_k(
        const float* __restrict__ img, const float* __restrict__ txt,
        const float* __restrict__ cr, const int* __restrict__ labels,
        const float* __restrict__ margin,
        const float* rnImg, const float* rnTxt, const float* rnCr,
        const float* dgSim, const float* dgCr, const float* mgCr,
        const int* stragCnt, const int* stragList,
        unsigned long long* negIdx64) {
    __shared__ __align__(16) float Aload[8][ND];   // 16 KB
    __shared__ float sRn[8], sDg[8], sMg[8];
    __shared__ int   sLab[8], sAid[8];
    __shared__ float colRn_s[32];
    __shared__ int   colLab_s[32];
    __shared__ int   sSurv[256];
    __shared__ int   sNa;

    const int tid = threadIdx.x, z = blockIdx.y;
    const int c0 = WSTART + blockIdx.x * 32;
    int cnt = stragCnt[z];
    if (cnt <= 0) return;
    cnt = min(cnt, NB);                        // replay-safe clamp
    // wina fully covered [WSTART,WCOLS) unless its capacity overflowed
    if (cnt <= WCAP && c0 < WCOLS) return;

    const float *A, *B, *rnA, *rnB, *dgA, *mgA;
    pass_arrays(z, img, txt, cr, rnImg, rnTxt, rnCr, dgSim, dgCr, margin, mgCr,
                A, B, rnA, rnB, dgA, mgA);

    // survivor compaction (order irrelevant: result is a global min)
    if (tid == 0) sNa = 0;
    __syncthreads();
    for (int s = tid; s < cnt; s += 256) {
        int a = stragList[z * NB + s];
        if ((unsigned)a < NB && negIdx64[z * NB + a] == PK_NONE) {
            int p = atomicAdd(&sNa, 1);
            if (p < 256) sSurv[p] = a;
        }
    }
    __syncthreads();
    const int na = min(sNa, 256);
    if (na == 0) return;

    if (tid < 32) { colRn_s[tid] = rnB[c0 + tid]; colLab_s[tid] = labels[c0 + tid]; }

    const int wv = tid >> 6, lane = tid & 63;

    for (int g0 = 0; g0 < na; g0 += 8) {
        const int gn = min(8, na - g0);
        __syncthreads();                       // protect Aload/params reuse
        if (tid < 8) {
            int s = g0 + ((tid < gn) ? tid : 0);
            int a = sSurv[s];
            sAid[tid] = (tid < gn) ? a : -1;
            sRn[tid] = rnA[a]; sDg[tid] = dgA[a]; sMg[tid] = mgA[a];
            sLab[tid] = labels[a];
        }
        #pragma unroll
        for (int m = 0; m < 4; ++m) {          // stage gn survivor rows
            int idx = tid + m * 256;
            int row = idx >> 7, f4 = idx & 127;
            if (row < gn) {
                int a = sSurv[g0 + row];
                *(float4*)&Aload[row][f4 * 4] =
                    *(const float4*)(A + (size_t)a * ND + f4 * 4);
            }
        }
        __syncthreads();

        // each wave: 8 cols, in batches of 4 (B loads shared across survivors)
        #pragma unroll
        for (int cb = 0; cb < 2; ++cb) {
            const int cc0 = wv * 8 + cb * 4;
            float4 b0[4], b1[4];
            #pragma unroll
            for (int q = 0; q < 4; ++q) {
                const float4* Bv = (const float4*)(B + (size_t)(c0 + cc0 + q) * ND);
                b0[q] = Bv[lane]; b1[q] = Bv[lane + 64];
            }
            for (int s = 0; s < gn; ++s) {     // gn-bounded: no padding work
                float4 a0v = *(const float4*)&Aload[s][lane * 4];
                float4 a1v = *(const float4*)&Aload[s][(lane + 64) * 4];
                float d0 = dot8(a0v, a1v, b0[0], b1[0]);
                float d1 = dot8(a0v, a1v, b0[1], b1[1]);
                float d2 = dot8(a0v, a1v, b0[2], b1[2]);
                float d3 = dot8(a0v, a1v, b0[3], b1[3]);
                #pragma unroll
                for (int off = 1; off < 64; off <<= 1) {
                    d0 += __shfl_xor(d0, off); d1 += __shfl_xor(d1, off);
                    d2 += __shfl_xor(d2, off); d3 += __shfl_xor(d3, off);
                }
                if (lane == 0) {
                    int aid = sAid[s];
                    float rn = sRn[s], dg = sDg[s], mg = sMg[s];
                    int lb = sLab[s];
                    float dv[4] = {d0, d1, d2, d3};
                    #pragma unroll
                    for (int q = 0; q < 4; ++q) {
                        int cc = cc0 + q;
                        if (colLab_s[cc] != lb) {
                            float lm = dv[q] * rn * colRn_s[cc] - dg + mg;
                            if (lm > 0.0f && lm < mg)
                                atomicMin(&negIdx64[z * NB + aid],
                                          pack_cand(c0 + cc, lm));
                        }
                    }
                }
            }
        }
    }
}

// ---------------------------------------------------------------------------
// final: sum stored (col,lm) payloads per straggler — NO dot recompute
// (R10-measured win). Cross-kernel stream ordering makes plain loads coherent.
// ---------------------------------------------------------------------------
__global__ __launch_bounds__(256) void final_k(
        const float* __restrict__ betap,
        const int* stragCnt, const int* stragList,
        const unsigned long long* negIdx64, float* out) {
    __shared__ float s4[4];
    const int tid = threadIdx.x, z = blockIdx.y;
    int cnt = stragCnt[z];
    cnt = (cnt < 0) ? 0 : min(cnt, NB);        // replay-safe clamp
    int t = blockIdx.x * 256 + tid;
    float contrib = 0.0f;
    if (t < cnt) {
        int a = stragList[z * NB + t];
        if ((unsigned)a < NB) {
            unsigned long long pk = negIdx64[z * NB + a];
            if (pk != PK_NONE) {
                unsigned col = (unsigned)(pk >> 32);
                if (col < NB) {                // replay-safe sanity
                    float lm = __uint_as_float((unsigned)(pk & 0xFFFFFFFFu));
                    contrib = fmaxf(lm, 0.0f); // 0<lm<mg => relu identity
                }
            }
        }
    }
    #pragma unroll
    for (int off = 32; off; off >>= 1) contrib += __shfl_xor(contrib, off);
    if ((tid & 63) == 0) s4[tid >> 6] = contrib;
    __syncthreads();
    if (tid == 0) {
        float sum = s4[0] + s4[1] + s4[2] + s4[3];
        if (sum != 0.0f) atomicAdd(out, sum * ((z >= 2) ? betap[0] : 1.0f));
    }
}

// ===========================================================================
// Fallback path (no workspace) — the proven round-3 single-kernel version.
// ===========================================================================

__global__ __launch_bounds__(256) void zero_k(float* out, int n) {
    int g = blockIdx.x * 256 + threadIdx.x;
    if (g < n) out[g] = 0.0f;
}

template <int U>
__device__ void stragScan(const float* __restrict__ A, const float* __restrict__ B,
                          const int* __restrict__ labels, int a0, int u, int scol,
                          const int* sList, int g0,
                          const float* aRn, const float* aDg, const float* aMg,
                          const int* aLab, int* sMin8, int* doneMask,
                          float* blockAcc) {
    const int tid = threadIdx.x;
    float rn_s[U], dg_s[U], mg_s[U];
    int lab_s[U];
    const float4* Av[U];
    #pragma unroll
    for (int s = 0; s < U; ++s) {
        int slot = sList[g0 + (s < u ? s : 0)];
        rn_s[s] = aRn[slot]; dg_s[s] = aDg[slot]; mg_s[s] = aMg[slot];
        lab_s[s] = aLab[slot];
        Av[s] = (const float4*)(A + (size_t)(a0 + slot) * ND);
    }
    if (tid < U) sMin8[tid] = INT_MAX;
    if (tid == 0) *doneMask = 0;
    __syncthreads();
    for (int jb = scol; jb < NB; jb += 256) {
        int j = jb + tid;
        bool jv = (j < NB);
        int mask = *doneMask;
        float dot[U];
        #pragma unroll
        for (int s = 0; s < U; ++s) dot[s] = 0.0f;
        float ssq = 0.0f;
        if (jv) {
            const float4* Bv = (const float4*)(B + (size_t)j * ND);
            #pragma unroll 4
            for (int k4 = 0; k4 < ND / 4; ++k4) {
                float4 b = Bv[k4];
                ssq += b.x*b.x + b.y*b.y + b.z*b.z + b.w*b.w;
                #pragma unroll
                for (int s = 0; s < U; ++s) {
                    float4 a = Av[s][k4];
                    dot[s] += a.x*b.x + a.y*b.y + a.z*b.z + a.w*b.w;
                }
            }
        }
        float rnb = 1.0f / (sqrtf(ssq) + 1e-8f);
        int lj = jv ? labels[j] : -1;
        float lmv[U];
        #pragma unroll
        for (int s = 0; s < U; ++s) {
            lmv[s] = dot[s] * rn_s[s] * rnb - dg_s[s] + mg_s[s];
            if (jv && s < u && !((mask >> s) & 1) && lj != lab_s[s] &&
                lmv[s] > 0.0f && lmv[s] < mg_s[s])
                atomicMin(&sMin8[s], j);
        }
        __syncthreads();
        #pragma unroll
        for (int s = 0; s < U; ++s)
            if (jv && s < u && !((mask >> s) & 1) && sMin8[s] == j)
                atomicAdd(blockAcc, lmv[s]);
        __syncthreads();
        if (tid == 0) {
            int m2 = 0;
            for (int s = 0; s < u; ++s)
                if (sMin8[s] != INT_MAX) m2 |= (1 << s);
            *doneMask = m2;
        }
        __syncthreads();
        if (*doneMask == (1 << u) - 1) break;
    }
}

__global__ __launch_bounds__(256) void mine_k(const float* __restrict__ img,
                                              const float* __restrict__ txt,
                                              const float* __restrict__ cr,
                                              const int*   __restrict__ labels,
                                              const int*   __restrict__ flagp,
                                              const float* __restrict__ margin,
                                              const float* __restrict__ betap,
                                              float* __restrict__ out) {
    __shared__ __align__(16) float As[16][64];
    __shared__ __align__(16) float Bs[16][64];
    __shared__ float aRn[64], aDg[64], aMg[64];
    __shared__ int   aLab[64];
    __shared__ float colRn[64];
    __shared__ int   colLab[64];
    __shared__ int   resIdx[64], prevIdx[64];
    __shared__ int   cnt;
    __shared__ float blockAcc;
    __shared__ int   sList[64];
    __shared__ int   sCnt;
    __shared__ int   sMin8[8];
    __shared__ int   doneMask;

    const int tid  = threadIdx.x;
    const int z    = blockIdx.y;
    const int a0   = blockIdx.x * 64;
    const int flag = flagp[0];
    const float* A = (z == 1) ? txt : (z == 3) ? cr : img;
    const float* B = (z == 0) ? txt : (z == 2) ? cr : img;
    {
        int ar = tid >> 2, q = tid & 3;
        int a  = a0 + ar;
        const float4* iv = (const float4*)(img + (size_t)a * ND) + q * 32;
        const float4* tv = (const float4*)(txt + (size_t)a * ND) + q * 32;
        const float4* cv = (const float4*)(cr  + (size_t)a * ND) + q * 32;
        float sii = 0, stt = 0, scc = 0, sit = 0, sic = 0;
        #pragma unroll 4
        for (int i = 0; i < 32; ++i) {
            float4 x = iv[i], y = tv[i], w = cv[i];
            sii += x.x*x.x + x.y*x.y + x.z*x.z + x.w*x.w;
            stt += y.x*y.x + y.y*y.y + y.z*y.z + y.w*y.w;
            scc += w.x*w.x + w.y*w.y + w.z*w.z + w.w*w.w;
            sit += x.x*y.x + x.y*y.y + x.z*y.z + x.w*y.w;
            sic += x.x*w.x + x.y*w.y + x.z*w.z + x.w*w.w;
        }
        sii += __shfl_xor(sii, 1); sii += __shfl_xor(sii, 2);
        stt += __shfl_xor(stt, 1); stt += __shfl_xor(stt, 2);
        sit += __shfl_xor(sit, 1); sit += __shfl_xor(sit, 2);
        scc += __shfl_xor(scc, 1); scc += __shfl_xor(scc, 2);
        sic += __shfl_xor(sic, 1); sic += __shfl_xor(sic, 2);
        if (q == 0) {
            float rnI = 1.0f / (sqrtf(sii) + 1e-8f);
            float rnT = 1.0f / (sqrtf(stt) + 1e-8f);
            float ds  = sit * rnI * rnT;
            float m   = margin[a];
            float mg, rna, dgv;
            if (z >= 2) {
                float rnC = 1.0f / (sqrtf(scc) + 1e-8f);
                float dc  = sic * rnI * rnC;
                mg = flag ? (fminf(fabsf(dc) / fabsf(ds), 1.0f) + 1.0f) * m * 0.5f
                          : m * 0.5f;
                dgv = dc; rna = (z == 3) ? rnC : rnI;
            } else {
                mg = m; dgv = ds; rna = (z == 1) ? rnT : rnI;
            }
            aRn[ar] = rna; aDg[ar] = dgv; aMg[ar] = mg; aLab[ar] = labels[a];
            resIdx[ar] = (flag && mg < 0.16f) ? -1 : INT_MAX;
        }
        if (tid == 0) blockAcc = 0.0f;
    }
    __syncthreads();
    const int ty4  = (tid >> 4) * 4, tx4 = (tid & 15) * 4;
    const int lrow = tid >> 2,  lk4 = (tid & 3) * 4;
    int bandCols = 0, unresolved = 64;
    for (int jc = 0; jc < 2; ++jc) {
        int j0 = jc * 64;
        float acc[4][4];
        #pragma unroll
        for (int i = 0; i < 4; ++i)
            #pragma unroll
            for (int j = 0; j < 4; ++j) acc[i][j] = 0.0f;
        float bssq = 0.0f;
        for (int kc = 0; kc < ND; kc += 16) {
            __syncthreads();
            float4 va = *(const float4*)(A + (size_t)(a0 + lrow) * ND + kc + lk4);
            float4 vb = *(const float4*)(B + (size_t)(j0 + lrow) * ND + kc + lk4);
            As[lk4 + 0][lrow] = va.x; As[lk4 + 1][lrow] = va.y;
            As[lk4 + 2][lrow] = va.z; As[lk4 + 3][lrow] = va.w;
            Bs[lk4 + 0][lrow] = vb.x; Bs[lk4 + 1][lrow] = vb.y;
            Bs[lk4 + 2][lrow] = vb.z; Bs[lk4 + 3][lrow] = vb.w;
            bssq += vb.x*vb.x + vb.y*vb.y + vb.z*vb.z + vb.w*vb.w;
            __syncthreads();
            #pragma unroll
            for (int k = 0; k < 16; ++k) {
                float4 av = *(const float4*)&As[k][ty4];
                float4 bv = *(const float4*)&Bs[k][tx4];
                float ar[4] = {av.x, av.y, av.z, av.w};
                float br[4] = {bv.x, bv.y, bv.z, bv.w};
                #pragma unroll
                for (int i = 0; i < 4; ++i)
                    #pragma unroll
                    for (int j = 0; j < 4; ++j)
                        acc[i][j] = fmaf(ar[i], br[j], acc[i][j]);
            }
        }
        bssq += __shfl_xor(bssq, 1); bssq += __shfl_xor(bssq, 2);
        __syncthreads();
        if ((tid & 3) == 0) {
            colRn[lrow]  = 1.0f / (sqrtf(bssq) + 1e-8f);
            colLab[lrow] = labels[j0 + lrow];
        }
        if (tid < 64) prevIdx[tid] = resIdx[tid];
        __syncthreads();
        #pragma unroll
        for (int i = 0; i < 4; ++i) {
            int r = ty4 + i;
            if (prevIdx[r] != INT_MAX) continue;
            float dg = aDg[r], mgv = aMg[r], rna = aRn[r];
            int la = aLab[r];
            #pragma unroll
            for (int j = 0; j < 4; ++j) {
                int c = tx4 + j;
                if (colLab[c] == la) continue;
                float v  = acc[i][j] * rna * colRn[c];
                float lm = v - dg + mgv;
                if (lm > 0.0f && lm < mgv) atomicMin(&resIdx[r], j0 + c);
            }
        }
        __syncthreads();
        #pragma unroll
        for (int i = 0; i < 4; ++i) {
            int r = ty4 + i;
            if (prevIdx[r] != INT_MAX) continue;
            int w = resIdx[r];
            if (w == INT_MAX) continue;
            int c = w - j0 - tx4;
            if (c < 0 || c > 3) continue;
            float v  = acc[i][c] * aRn[r] * colRn[tx4 + c];
            float lm = v - aDg[r] + aMg[r];
            atomicAdd(&blockAcc, lm);
        }
        __syncthreads();
        if (tid == 0) cnt = 0;
        __syncthreads();
        if (tid < 64 && resIdx[tid] == INT_MAX) atomicAdd(&cnt, 1);
        __syncthreads();
        unresolved = cnt;
        bandCols = j0 + 64;
        __syncthreads();
        if (unresolved <= 8) break;
    }
    if (unresolved > 0) {
        if (tid == 0) sCnt = 0;
        __syncthreads();
        if (tid < 64 && resIdx[tid] == INT_MAX) {
            int pos = atomicAdd(&sCnt, 1);
            sList[pos] = tid;
        }
        __syncthreads();
        int total = sCnt;
        for (int g0 = 0; g0 < total; g0 += 8) {
            int u = min(8, total - g0);
            if (u == 1)      stragScan<1>(A, B, labels, a0, u, bandCols, sList, g0, aRn, aDg, aMg, aLab, sMin8, &doneMask, &blockAcc);
            else if (u == 2) stragScan<2>(A, B, labels, a0, u, bandCols, sList, g0, aRn, aDg, aMg, aLab, sMin8, &doneMask, &blockAcc);
            else if (u <= 4) stragScan<4>(A, B, labels, a0, u, bandCols, sList, g0, aRn, aDg, aMg, aLab, sMin8, &doneMask, &blockAcc);
            else             stragScan<8>(A, B, labels, a0, u, bandCols, sList, g0, aRn, aDg, aMg, aLab, sMin8, &doneMask, &blockAcc);
            __syncthreads();
        }
    }
    if (tid == 0 && blockAcc != 0.0f) {
        float scale = (z >= 2) ? betap[0] : 1.0f;
        atomicAdd(out, blockAcc * scale);
    }
}

// ===========================================================================

extern "C" void kernel_launch(void* const* d_in, const int* in_sizes, int n_in,
                              void* d_out, int out_size, void* d_ws, size_t ws_size,
                              hipStream_t stream) {
    const float* img    = (const float*)d_in[0];
    const float* txt    = (const float*)d_in[1];
    const float* cr     = (const float*)d_in[2];
    const int*   labels = (const int*)  d_in[3];
    const int*   flagp  = (const int*)  d_in[4];
    const float* marg   = (const float*)d_in[5];
    const float* betap  = (const float*)d_in[6];
    float* out = (float*)d_out;
    (void)in_sizes; (void)n_in;

    const size_t REQ = (size_t)(6 * NB) * 4 + (size_t)(4 * NB) * 8 + 64 +
                       (size_t)(4 * NB) * 4;
    if (ws_size >= REQ) {
        float* wf = (float*)d_ws;
        float* rnImg = wf + 0 * NB;
        float* rnTxt = wf + 1 * NB;
        float* rnCr  = wf + 2 * NB;
        float* dgSim = wf + 3 * NB;
        float* dgCr  = wf + 4 * NB;
        float* mgCr  = wf + 5 * NB;
        unsigned long long* negIdx64 = (unsigned long long*)(wf + 6 * NB);
        int* stragCnt  = (int*)(negIdx64 + 4 * NB);
        int* stragList = stragCnt + 16;

        stats_k<<<dim3(NB / 16),              dim3(256), 0, stream>>>(
            img, txt, cr, marg, flagp,
            rnImg, rnTxt, rnCr, dgSim, dgCr, mgCr, negIdx64, stragCnt, out);
        band_k <<<dim3(NB / 64, 4),           dim3(256), 0, stream>>>(
            img, txt, cr, labels, flagp, marg, betap,
            rnImg, rnTxt, rnCr, dgSim, dgCr, mgCr, stragCnt, stragList, out);
        wina_k <<<dim3(WCHUNKS * WTILES, 4),  dim3(256), 0, stream>>>(
            img, txt, cr, labels, marg,
            rnImg, rnTxt, rnCr, dgSim, dgCr, mgCr,
            stragCnt, stragList, negIdx64);
        tail_k <<<dim3(TCHUNKS, 4),           dim3(256), 0, stream>>>(
            img, txt, cr, labels, marg,
            rnImg, rnTxt, rnCr, dgSim, dgCr, mgCr,
            stragCnt, stragList, negIdx64);
        final_k<<<dim3(NB / 256, 4),          dim3(256), 0, stream>>>(
            betap, stragCnt, stragList, negIdx64, out);
    } else {
        zero_k<<<dim3((out_size + 255) / 256), dim3(256), 0, stream>>>(out, out_size);
        mine_k<<<dim3(NB / 64, 4), dim3(256), 0, stream>>>(img, txt, cr, labels,
                                                           flagp, marg, betap, out);
    }
}

// Round 15
// 194.039 us; speedup vs baseline: 1.1338x; 1.1218x over previous
//
#include <hip/hip_runtime.h>
#include <climits>

// Problem constants (fixed by the reference): B=8192 rows, D=512 features.
#define NB 8192
#define ND 512

// Straggler resolution:
//   wina_k: cols [64, 64+WCHUNKS*32) = [64,1088), up to WTILES*64 stragglers/z
//   tail_k: cols [64, NB) for the survivors, 32-col chunks; skips [64,1088)
//           unless wina capacity overflowed.
#define WCHUNKS 32
#define WTILES 4
#define WCAP (WTILES * 64)          // 256 stragglers/z
#define WCOLS (64 + WCHUNKS * 32)   // 1088
#define TCHUNKS ((NB - 64) / 32)    // 254

#define PK_NONE (~0ULL)

// pack (col, lm) so u64 atomicMin selects min col; lm>0 => bits monotone.
__device__ inline unsigned long long pack_cand(int col, float lm) {
    return ((unsigned long long)(unsigned)col << 32) |
           (unsigned long long)__float_as_uint(lm);
}

// ===========================================================================
// Fast path: stats -> band -> wina -> tail -> final through d_ws.
// ws layout: floats rnImg rnTxt rnCr dgSim dgCr mgCr [6*NB];
//            u64 negIdx64 [4*NB]; int stragCnt [16]; int stragList [4*NB]
// ===========================================================================

// Per-row stats + workspace init. 16 threads/row, 16 rows/block, 512 blocks.
__global__ __launch_bounds__(256) void stats_k(
        const float* __restrict__ img, const float* __restrict__ txt,
        const float* __restrict__ cr, const float* __restrict__ margin,
        const int* __restrict__ flagp,
        float* rnImg, float* rnTxt, float* rnCr,
        float* dgSim, float* dgCr, float* mgCr,
        unsigned long long* negIdx64, int* stragCnt, float* out) {
    int tid = threadIdx.x, bid = blockIdx.x;
    int g = bid * 256 + tid;
    if (g < 4 * NB) negIdx64[g] = PK_NONE;
    if (bid == 0 && tid < 16) stragCnt[tid] = 0;
    if (bid == 0 && tid == 0) out[0] = 0.0f;

    int r = bid * 16 + (tid >> 4);
    int q = tid & 15;
    const float4* iv = (const float4*)(img + (size_t)r * ND);
    const float4* tv = (const float4*)(txt + (size_t)r * ND);
    const float4* cv = (const float4*)(cr  + (size_t)r * ND);
    float sii = 0, stt = 0, scc = 0, sit = 0, sic = 0;
    #pragma unroll
    for (int i = 0; i < 8; ++i) {                 // lane-contiguous: coalesced
        int k = q + i * 16;
        float4 x = iv[k], y = tv[k], w = cv[k];
        sii += x.x*x.x + x.y*x.y + x.z*x.z + x.w*x.w;
        stt += y.x*y.x + y.y*y.y + y.z*y.z + y.w*y.w;
        scc += w.x*w.x + w.y*w.y + w.z*w.z + w.w*w.w;
        sit += x.x*y.x + x.y*y.y + x.z*y.z + x.w*y.w;
        sic += x.x*w.x + x.y*w.y + x.z*w.z + x.w*w.w;
    }
    #pragma unroll
    for (int off = 1; off < 16; off <<= 1) {
        sii += __shfl_xor(sii, off); stt += __shfl_xor(stt, off);
        scc += __shfl_xor(scc, off); sit += __shfl_xor(sit, off);
        sic += __shfl_xor(sic, off);
    }
    if (q == 0) {
        float rnI = 1.0f / (sqrtf(sii) + 1e-8f);
        float rnT = 1.0f / (sqrtf(stt) + 1e-8f);
        float rnC = 1.0f / (sqrtf(scc) + 1e-8f);
        float ds = sit * rnI * rnT;
        float dc = sic * rnI * rnC;
        float m  = margin[r];
        float mcr = flagp[0] ? (fminf(fabsf(dc) / fabsf(ds), 1.0f) + 1.0f) * m * 0.5f
                             : m * 0.5f;
        rnImg[r] = rnI; rnTxt[r] = rnT; rnCr[r] = rnC;
        dgSim[r] = ds;  dgCr[r]  = dc;  mgCr[r] = mcr;
    }
}

__device__ inline void pass_arrays(int z,
        const float* img, const float* txt, const float* cr,
        const float* rnImg, const float* rnTxt, const float* rnCr,
        const float* dgSim, const float* dgCr,
        const float* margin, const float* mgCr,
        const float*& A, const float*& B, const float*& rnA, const float*& rnB,
        const float*& dgA, const float*& mgA) {
    if (z == 0)      { A = img; B = txt; rnA = rnImg; rnB = rnTxt; dgA = dgSim; mgA = margin; }
    else if (z == 1) { A = txt; B = img; rnA = rnTxt; rnB = rnImg; dgA = dgSim; mgA = margin; }
    else if (z == 2) { A = img; B = cr;  rnA = rnImg; rnB = rnCr;  dgA = dgCr;  mgA = mgCr;   }
    else             { A = cr;  B = img; rnA = rnCr;  rnB = rnImg; dgA = dgCr;  mgA = mgCr;   }
}

// ---------------------------------------------------------------------------
// band (R15): R12's proven 64x64 acc[4][4] tile + LDS DOUBLE-BUFFER.
// One barrier per kc (was 2): write buf[cur^1] from prefetched regs,
// prefetch kc+32, compute buf[cur], barrier. Same staging addresses
// (2-way-free), same fmaf chain (bit-exact). LDS ~19.5KB -> 2 blocks/CU.
// ---------------------------------------------------------------------------
__global__ __launch_bounds__(256) void band_k(
        const float* __restrict__ img, const float* __restrict__ txt,
        const float* __restrict__ cr, const int* __restrict__ labels,
        const int* __restrict__ flagp, const float* __restrict__ margin,
        const float* __restrict__ betap,
        const float* rnImg, const float* rnTxt, const float* rnCr,
        const float* dgSim, const float* dgCr, const float* mgCr,
        int* stragCnt, int* stragList, float* out) {
    __shared__ __align__(16) float As[2][16][68];
    __shared__ __align__(16) float Bs[2][16][68];
    __shared__ float aRn[64], aDg[64], aMg[64], colRn[64];
    __shared__ int   aLab[64], colLab[64], resIdx[64];
    __shared__ float blockAcc;

    const int tid = threadIdx.x, z = blockIdx.y, a0 = blockIdx.x * 64;
    const int flag = flagp[0];
    const float *A, *B, *rnA, *rnB, *dgA, *mgA;
    pass_arrays(z, img, txt, cr, rnImg, rnTxt, rnCr, dgSim, dgCr, margin, mgCr,
                A, B, rnA, rnB, dgA, mgA);

    if (tid < 64) {
        int a = a0 + tid;
        float mg = mgA[a];
        aRn[tid] = rnA[a]; aDg[tid] = dgA[a]; aMg[tid] = mg;
        aLab[tid] = labels[a];
        colRn[tid] = rnB[tid]; colLab[tid] = labels[tid];
        resIdx[tid] = (flag && mg < 0.16f) ? -1 : INT_MAX;
    }
    if (tid == 0) blockAcc = 0.0f;

    const int ty4  = (tid >> 4) * 4, tx4 = (tid & 15) * 4;
    const int lrow = tid >> 2,  lk4 = (tid & 3) * 4;
    const float* Arow = A + (size_t)(a0 + lrow) * ND + lk4;
    const float* Brow = B + (size_t)lrow * ND + lk4;

    float acc[4][4];
    #pragma unroll
    for (int i = 0; i < 4; ++i)
        #pragma unroll
        for (int j = 0; j < 4; ++j) acc[i][j] = 0.0f;

    // prologue: stage kc=0 into buf0; prefetch kc=16 into regs
    {
        float4 va = *(const float4*)(Arow);
        float4 vb = *(const float4*)(Brow);
        As[0][lk4 + 0][lrow] = va.x; As[0][lk4 + 1][lrow] = va.y;
        As[0][lk4 + 2][lrow] = va.z; As[0][lk4 + 3][lrow] = va.w;
        Bs[0][lk4 + 0][lrow] = vb.x; Bs[0][lk4 + 1][lrow] = vb.y;
        Bs[0][lk4 + 2][lrow] = vb.z; Bs[0][lk4 + 3][lrow] = vb.w;
    }
    float4 va = *(const float4*)(Arow + 16);
    float4 vb = *(const float4*)(Brow + 16);
    __syncthreads();                           // header + buf0 ready

    int cur = 0;
    for (int kc = 0; kc < ND; kc += 16) {
        if (kc + 16 < ND) {
            // write NEXT buffer from regs prefetched last iteration
            As[cur ^ 1][lk4 + 0][lrow] = va.x; As[cur ^ 1][lk4 + 1][lrow] = va.y;
            As[cur ^ 1][lk4 + 2][lrow] = va.z; As[cur ^ 1][lk4 + 3][lrow] = va.w;
            Bs[cur ^ 1][lk4 + 0][lrow] = vb.x; Bs[cur ^ 1][lk4 + 1][lrow] = vb.y;
            Bs[cur ^ 1][lk4 + 2][lrow] = vb.z; Bs[cur ^ 1][lk4 + 3][lrow] = vb.w;
            if (kc + 32 < ND) {                // prefetch two-ahead
                va = *(const float4*)(Arow + kc + 32);
                vb = *(const float4*)(Brow + kc + 32);
            }
        }
        #pragma unroll
        for (int k = 0; k < 16; ++k) {
            float4 av = *(const float4*)&As[cur][k][ty4];
            float4 bv = *(const float4*)&Bs[cur][k][tx4];
            float ar[4] = {av.x, av.y, av.z, av.w};
            float br[4] = {bv.x, bv.y, bv.z, bv.w};
            #pragma unroll
            for (int i = 0; i < 4; ++i)
                #pragma unroll
                for (int j = 0; j < 4; ++j)
                    acc[i][j] = fmaf(ar[i], br[j], acc[i][j]);
        }
        __syncthreads();                       // next buf written / cur free
        cur ^= 1;
    }

    // predicate pass: first valid (min col) via atomicMin
    #pragma unroll
    for (int i = 0; i < 4; ++i) {
        int r = ty4 + i;
        float mgv = aMg[r];
        if (flag && mgv < 0.16f) continue;     // pre-resolved: contributes 0
        float dg = aDg[r], rna = aRn[r];
        int la = aLab[r];
        #pragma unroll
        for (int j = 0; j < 4; ++j) {
            int c = tx4 + j;
            if (colLab[c] == la) continue;
            float lm = acc[i][j] * rna * colRn[c] - dg + mgv;
            if (lm > 0.0f && lm < mgv) atomicMin(&resIdx[r], c);
        }
    }
    __syncthreads();

    // winner pass: unique owner thread of the winning column adds lm
    #pragma unroll
    for (int i = 0; i < 4; ++i) {
        int r = ty4 + i;
        int w = resIdx[r];
        if (w < 0 || w == INT_MAX) continue;
        int c = w - tx4;
        if (c < 0 || c > 3) continue;
        float lm = acc[i][c] * aRn[r] * colRn[w] - aDg[r] + aMg[r];
        atomicAdd(&blockAcc, lm);
    }
    __syncthreads();

    if (tid < 64 && resIdx[tid] == INT_MAX) {  // unresolved -> global straggler
        int pos = atomicAdd(&stragCnt[z], 1);
        stragList[z * NB + pos] = a0 + tid;
    }
    if (tid == 0 && blockAcc != 0.0f) {
        float scale = (z >= 2) ? betap[0] : 1.0f;
        atomicAdd(out, blockAcc * scale);
    }
}

// ---------------------------------------------------------------------------
// wina: gathered 64-straggler tiles x 32-col chunks over [64,1088).
// Grid (WCHUNKS*WTILES, 4) = 512 blocks; inactive tiles exit immediately.
// Candidates stored as packed (col, lm) u64 — enables recompute-free final.
// ---------------------------------------------------------------------------
__global__ __launch_bounds__(256) void wina_k(
        const float* __restrict__ img, const float* __restrict__ txt,
        const float* __restrict__ cr, const int* __restrict__ labels,
        const float* __restrict__ margin,
        const float* rnImg, const float* rnTxt, const float* rnCr,
        const float* dgSim, const float* dgCr, const float* mgCr,
        const int* stragCnt, const int* stragList,
        unsigned long long* negIdx64) {
    __shared__ __align__(16) float As[16][68];
    __shared__ __align__(16) float Bs[16][36];
    __shared__ float aRn[64], aDg[64], aMg[64], colRn[32];
    __shared__ int   aId[64], aRow[64], aLab[64], colLab[32];

    const int tid = threadIdx.x, z = blockIdx.y;
    const int chunk = blockIdx.x & (WCHUNKS - 1);
    const int t     = blockIdx.x / WCHUNKS;
    int cnt = stragCnt[z];
    if (cnt <= 0) return;
    cnt = min(cnt, NB);                        // replay-safe clamp
    if (t * 64 >= cnt) return;                 // uniform: no anchors here
    const int c0 = 64 + chunk * 32;

    const float *A, *B, *rnA, *rnB, *dgA, *mgA;
    pass_arrays(z, img, txt, cr, rnImg, rnTxt, rnCr, dgSim, dgCr, margin, mgCr,
                A, B, rnA, rnB, dgA, mgA);

    if (tid < 64) {
        int s = t * 64 + tid;
        int a = (s < cnt) ? stragList[z * NB + s] : -1;
        if ((unsigned)a >= NB) a = -1;         // replay-safe bound
        int ar = (a >= 0) ? a : 0;             // dummy row for padding lanes
        aId[tid] = a; aRow[tid] = ar;
        aRn[tid] = rnA[ar]; aDg[tid] = dgA[ar]; aMg[tid] = mgA[ar];
        aLab[tid] = labels[ar];
    }
    if (tid < 32) { colRn[tid] = rnB[c0 + tid]; colLab[tid] = labels[c0 + tid]; }
    __syncthreads();

    const int ty4  = (tid >> 4) * 4, tx2 = (tid & 15) * 2;
    const int lrow = tid >> 2,  lk4 = (tid & 3) * 4;
    const int arow = aRow[lrow];
    const bool doB = tid < 128;                // 32 B-rows x 4 f4-chunks

    float acc[4][2];
    #pragma unroll
    for (int i = 0; i < 4; ++i) { acc[i][0] = 0.0f; acc[i][1] = 0.0f; }

    float4 va = *(const float4*)(A + (size_t)arow * ND + lk4);
    float4 vb;
    if (doB) vb = *(const float4*)(B + (size_t)(c0 + lrow) * ND + lk4);
    for (int kc = 0; kc < ND; kc += 16) {
        __syncthreads();                       // prior compute done
        As[lk4 + 0][lrow] = va.x; As[lk4 + 1][lrow] = va.y;
        As[lk4 + 2][lrow] = va.z; As[lk4 + 3][lrow] = va.w;
        if (doB) {
            Bs[lk4 + 0][lrow] = vb.x; Bs[lk4 + 1][lrow] = vb.y;
            Bs[lk4 + 2][lrow] = vb.z; Bs[lk4 + 3][lrow] = vb.w;
        }
        if (kc + 16 < ND) {
            va = *(const float4*)(A + (size_t)arow * ND + kc + 16 + lk4);
            if (doB) vb = *(const float4*)(B + (size_t)(c0 + lrow) * ND + kc + 16 + lk4);
        }
        __syncthreads();
        #pragma unroll
        for (int k = 0; k < 16; ++k) {
            float4 av = *(const float4*)&As[k][ty4];
            float2 bv = *(const float2*)&Bs[k][tx2];
            float ar[4] = {av.x, av.y, av.z, av.w};
            #pragma unroll
            for (int i = 0; i < 4; ++i) {
                acc[i][0] = fmaf(ar[i], bv.x, acc[i][0]);
                acc[i][1] = fmaf(ar[i], bv.y, acc[i][1]);
            }
        }
    }
    __syncthreads();

    #pragma unroll
    for (int i = 0; i < 4; ++i) {
        int r = ty4 + i;
        int a = aId[r];
        if (a < 0) continue;
        float dg = aDg[r], mgv = aMg[r], rna = aRn[r];
        int la = aLab[r];
        #pragma unroll
        for (int j = 0; j < 2; ++j) {
            int c = tx2 + j;
            if (colLab[c] == la) continue;
            float lm = acc[i][j] * rna * colRn[c] - dg + mgv;
            if (lm > 0.0f && lm < mgv)
                atomicMin(&negIdx64[z * NB + a], pack_cand(c0 + c, lm));
        }
    }
}

__device__ inline float dot8(const float4& a0, const float4& a1,
                             const float4& b0, const float4& b1) {
    return a0.x*b0.x + a0.y*b0.y + a0.z*b0.z + a0.w*b0.w
         + a1.x*b1.x + a1.y*b1.y + a1.z*b1.z + a1.w*b1.w;
}

// ---------------------------------------------------------------------------
// tail: survivors of wina swept over 32-col chunks (254x4 blocks ~4/CU) —
// the R5-proven structure. gn-bounded survivor loop; A-stage only gn rows;
// wina-covered range skipped. Packed (col,lm) stores.
// ---------------------------------------------------------------------------
__global__ __launch_bounds__(256) void tail_k(
        const float* __restrict__ img, const float* __restrict__ txt,
        const float* __restrict__ cr, const int* __restrict__ labels,
        const float* __restrict__ margin,
        const float* rnImg, const float* rnTxt, const float* rnCr,
        const float* dgSim, const float* dgCr, const float* mgCr,
        const int* stragCnt, const int* stragList,
        unsigned long long* negIdx64) {
    __shared__ __align__(16) float Aload[8][ND];   // 16 KB
    __shared__ float sRn[8], sDg[8], sMg[8];
    __shared__ int   sLab[8], sAid[8];
    __shared__ float colRn_s[32];
    __shared__ int   colLab_s[32];
    __shared__ int   sSurv[256];
    __shared__ int   sNa;

    const int tid = threadIdx.x, z = blockIdx.y;
    const int c0 = 64 + blockIdx.x * 32;
    int cnt = stragCnt[z];
    if (cnt <= 0) return;
    cnt = min(cnt, NB);                        // replay-safe clamp
    // wina fully covered [64,1088) unless its capacity overflowed
    if (cnt <= WCAP && c0 < WCOLS) return;

    const float *A, *B, *rnA, *rnB, *dgA, *mgA;
    pass_arrays(z, img, txt, cr, rnImg, rnTxt, rnCr, dgSim, dgCr, margin, mgCr,
                A, B, rnA, rnB, dgA, mgA);

    // survivor compaction (order irrelevant: result is a global min)
    if (tid == 0) sNa = 0;
    __syncthreads();
    for (int s = tid; s < cnt; s += 256) {
        int a = stragList[z * NB + s];
        if ((unsigned)a < NB && negIdx64[z * NB + a] == PK_NONE) {
            int p = atomicAdd(&sNa, 1);
            if (p < 256) sSurv[p] = a;
        }
    }
    __syncthreads();
    const int na = min(sNa, 256);
    if (na == 0) return;

    if (tid < 32) { colRn_s[tid] = rnB[c0 + tid]; colLab_s[tid] = labels[c0 + tid]; }

    const int wv = tid >> 6, lane = tid & 63;

    for (int g0 = 0; g0 < na; g0 += 8) {
        const int gn = min(8, na - g0);
        __syncthreads();                       // protect Aload/params reuse
        if (tid < 8) {
            int s = g0 + ((tid < gn) ? tid : 0);
            int a = sSurv[s];
            sAid[tid] = (tid < gn) ? a : -1;
            sRn[tid] = rnA[a]; sDg[tid] = dgA[a]; sMg[tid] = mgA[a];
            sLab[tid] = labels[a];
        }
        #pragma unroll
        for (int m = 0; m < 4; ++m) {          // stage gn survivor rows
            int idx = tid + m * 256;
            int row = idx >> 7, f4 = idx & 127;
            if (row < gn) {
                int a = sSurv[g0 + row];
                *(float4*)&Aload[row][f4 * 4] =
                    *(const float4*)(A + (size_t)a * ND + f4 * 4);
            }
        }
        __syncthreads();

        // each wave: 8 cols, in batches of 4 (B loads shared across survivors)
        #pragma unroll
        for (int cb = 0; cb < 2; ++cb) {
            const int cc0 = wv * 8 + cb * 4;
            float4 b0[4], b1[4];
            #pragma unroll
            for (int q = 0; q < 4; ++q) {
                const float4* Bv = (const float4*)(B + (size_t)(c0 + cc0 + q) * ND);
                b0[q] = Bv[lane]; b1[q] = Bv[lane + 64];
            }
            for (int s = 0; s < gn; ++s) {     // gn-bounded: no padding work
                float4 a0v = *(const float4*)&Aload[s][lane * 4];
                float4 a1v = *(const float4*)&Aload[s][(lane + 64) * 4];
                float d0 = dot8(a0v, a1v, b0[0], b1[0]);
                float d1 = dot8(a0v, a1v, b0[1], b1[1]);
                float d2 = dot8(a0v, a1v, b0[2], b1[2]);
                float d3 = dot8(a0v, a1v, b0[3], b1[3]);
                #pragma unroll
                for (int off = 1; off < 64; off <<= 1) {
                    d0 += __shfl_xor(d0, off); d1 += __shfl_xor(d1, off);
                    d2 += __shfl_xor(d2, off); d3 += __shfl_xor(d3, off);
                }
                if (lane == 0) {
                    int aid = sAid[s];
                    float rn = sRn[s], dg = sDg[s], mg = sMg[s];
                    int lb = sLab[s];
                    float dv[4] = {d0, d1, d2, d3};
                    #pragma unroll
                    for (int q = 0; q < 4; ++q) {
                        int cc = cc0 + q;
                        if (colLab_s[cc] != lb) {
                            float lm = dv[q] * rn * colRn_s[cc] - dg + mg;
                            if (lm > 0.0f && lm < mg)
                                atomicMin(&negIdx64[z * NB + aid],
                                          pack_cand(c0 + cc, lm));
                        }
                    }
                }
            }
        }
    }
}

// ---------------------------------------------------------------------------
// final: sum stored (col,lm) payloads per straggler — NO dot recompute
// (R10-measured win). Cross-kernel stream ordering makes plain loads coherent.
// ---------------------------------------------------------------------------
__global__ __launch_bounds__(256) void final_k(
        const float* __restrict__ betap,
        const int* stragCnt, const int* stragList,
        const unsigned long long* negIdx64, float* out) {
    __shared__ float s4[4];
    const int tid = threadIdx.x, z = blockIdx.y;
    int cnt = stragCnt[z];
    cnt = (cnt < 0) ? 0 : min(cnt, NB);        // replay-safe clamp
    int t = blockIdx.x * 256 + tid;
    float contrib = 0.0f;
    if (t < cnt) {
        int a = stragList[z * NB + t];
        if ((unsigned)a < NB) {
            unsigned long long pk = negIdx64[z * NB + a];
            if (pk != PK_NONE) {
                unsigned col = (unsigned)(pk >> 32);
                if (col < NB) {                // replay-safe sanity
                    float lm = __uint_as_float((unsigned)(pk & 0xFFFFFFFFu));
                    contrib = fmaxf(lm, 0.0f); // 0<lm<mg => relu identity
                }
            }
        }
    }
    #pragma unroll
    for (int off = 32; off; off >>= 1) contrib += __shfl_xor(contrib, off);
    if ((tid & 63) == 0) s4[tid >> 6] = contrib;
    __syncthreads();
    if (tid == 0) {
        float sum = s4[0] + s4[1] + s4[2] + s4[3];
        if (sum != 0.0f) atomicAdd(out, sum * ((z >= 2) ? betap[0] : 1.0f));
    }
}

// ===========================================================================
// Fallback path (no workspace) — the proven round-3 single-kernel version.
// ===========================================================================

__global__ __launch_bounds__(256) void zero_k(float* out, int n) {
    int g = blockIdx.x * 256 + threadIdx.x;
    if (g < n) out[g] = 0.0f;
}

template <int U>
__device__ void stragScan(const float* __restrict__ A, const float* __restrict__ B,
                          const int* __restrict__ labels, int a0, int u, int scol,
                          const int* sList, int g0,
                          const float* aRn, const float* aDg, const float* aMg,
                          const int* aLab, int* sMin8, int* doneMask,
                          float* blockAcc) {
    const int tid = threadIdx.x;
    float rn_s[U], dg_s[U], mg_s[U];
    int lab_s[U];
    const float4* Av[U];
    #pragma unroll
    for (int s = 0; s < U; ++s) {
        int slot = sList[g0 + (s < u ? s : 0)];
        rn_s[s] = aRn[slot]; dg_s[s] = aDg[slot]; mg_s[s] = aMg[slot];
        lab_s[s] = aLab[slot];
        Av[s] = (const float4*)(A + (size_t)(a0 + slot) * ND);
    }
    if (tid < U) sMin8[tid] = INT_MAX;
    if (tid == 0) *doneMask = 0;
    __syncthreads();
    for (int jb = scol; jb < NB; jb += 256) {
        int j = jb + tid;
        bool jv = (j < NB);
        int mask = *doneMask;
        float dot[U];
        #pragma unroll
        for (int s = 0; s < U; ++s) dot[s] = 0.0f;
        float ssq = 0.0f;
        if (jv) {
            const float4* Bv = (const float4*)(B + (size_t)j * ND);
            #pragma unroll 4
            for (int k4 = 0; k4 < ND / 4; ++k4) {
                float4 b = Bv[k4];
                ssq += b.x*b.x + b.y*b.y + b.z*b.z + b.w*b.w;
                #pragma unroll
                for (int s = 0; s < U; ++s) {
                    float4 a = Av[s][k4];
                    dot[s] += a.x*b.x + a.y*b.y + a.z*b.z + a.w*b.w;
                }
            }
        }
        float rnb = 1.0f / (sqrtf(ssq) + 1e-8f);
        int lj = jv ? labels[j] : -1;
        float lmv[U];
        #pragma unroll
        for (int s = 0; s < U; ++s) {
            lmv[s] = dot[s] * rn_s[s] * rnb - dg_s[s] + mg_s[s];
            if (jv && s < u && !((mask >> s) & 1) && lj != lab_s[s] &&
                lmv[s] > 0.0f && lmv[s] < mg_s[s])
                atomicMin(&sMin8[s], j);
        }
        __syncthreads();
        #pragma unroll
        for (int s = 0; s < U; ++s)
            if (jv && s < u && !((mask >> s) & 1) && sMin8[s] == j)
                atomicAdd(blockAcc, lmv[s]);
        __syncthreads();
        if (tid == 0) {
            int m2 = 0;
            for (int s = 0; s < u; ++s)
                if (sMin8[s] != INT_MAX) m2 |= (1 << s);
            *doneMask = m2;
        }
        __syncthreads();
        if (*doneMask == (1 << u) - 1) break;
    }
}

__global__ __launch_bounds__(256) void mine_k(const float* __restrict__ img,
                                              const float* __restrict__ txt,
                                              const float* __restrict__ cr,
                                              const int*   __restrict__ labels,
                                              const int*   __restrict__ flagp,
                                              const float* __restrict__ margin,
                                              const float* __restrict__ betap,
                                              float* __restrict__ out) {
    __shared__ __align__(16) float As[16][64];
    __shared__ __align__(16) float Bs[16][64];
    __shared__ float aRn[64], aDg[64], aMg[64];
    __shared__ int   aLab[64];
    __shared__ float colRn[64];
    __shared__ int   colLab[64];
    __shared__ int   resIdx[64], prevIdx[64];
    __shared__ int   cnt;
    __shared__ float blockAcc;
    __shared__ int   sList[64];
    __shared__ int   sCnt;
    __shared__ int   sMin8[8];
    __shared__ int   doneMask;

    const int tid  = threadIdx.x;
    const int z    = blockIdx.y;
    const int a0   = blockIdx.x * 64;
    const int flag = flagp[0];
    const float* A = (z == 1) ? txt : (z == 3) ? cr : img;
    const float* B = (z == 0) ? txt : (z == 2) ? cr : img;
    {
        int ar = tid >> 2, q = tid & 3;
        int a  = a0 + ar;
        const float4* iv = (const float4*)(img + (size_t)a * ND) + q * 32;
        const float4* tv = (const float4*)(txt + (size_t)a * ND) + q * 32;
        const float4* cv = (const float4*)(cr  + (size_t)a * ND) + q * 32;
        float sii = 0, stt = 0, scc = 0, sit = 0, sic = 0;
        #pragma unroll 4
        for (int i = 0; i < 32; ++i) {
            float4 x = iv[i], y = tv[i], w = cv[i];
            sii += x.x*x.x + x.y*x.y + x.z*x.z + x.w*x.w;
            stt += y.x*y.x + y.y*y.y + y.z*y.z + y.w*y.w;
            scc += w.x*w.x + w.y*w.y + w.z*w.z + w.w*w.w;
            sit += x.x*y.x + x.y*y.y + x.z*y.z + x.w*y.w;
            sic += x.x*w.x + x.y*w.y + x.z*w.z + x.w*w.w;
        }
        sii += __shfl_xor(sii, 1); sii += __shfl_xor(sii, 2);
        stt += __shfl_xor(stt, 1); stt += __shfl_xor(stt, 2);
        sit += __shfl_xor(sit, 1); sit += __shfl_xor(sit, 2);
        scc += __shfl_xor(scc, 1); scc += __shfl_xor(scc, 2);
        sic += __shfl_xor(sic, 1); sic += __shfl_xor(sic, 2);
        if (q == 0) {
            float rnI = 1.0f / (sqrtf(sii) + 1e-8f);
            float rnT = 1.0f / (sqrtf(stt) + 1e-8f);
            float ds  = sit * rnI * rnT;
            float m   = margin[a];
            float mg, rna, dgv;
            if (z >= 2) {
                float rnC = 1.0f / (sqrtf(scc) + 1e-8f);
                float dc  = sic * rnI * rnC;
                mg = flag ? (fminf(fabsf(dc) / fabsf(ds), 1.0f) + 1.0f) * m * 0.5f
                          : m * 0.5f;
                dgv = dc; rna = (z == 3) ? rnC : rnI;
            } else {
                mg = m; dgv = ds; rna = (z == 1) ? rnT : rnI;
            }
            aRn[ar] = rna; aDg[ar] = dgv; aMg[ar] = mg; aLab[ar] = labels[a];
            resIdx[ar] = (flag && mg < 0.16f) ? -1 : INT_MAX;
        }
        if (tid == 0) blockAcc = 0.0f;
    }
    __syncthreads();
    const int ty4  = (tid >> 4) * 4, tx4 = (tid & 15) * 4;
    const int lrow = tid >> 2,  lk4 = (tid & 3) * 4;
    int bandCols = 0, unresolved = 64;
    for (int jc = 0; jc < 2; ++jc) {
        int j0 = jc * 64;
        float acc[4][4];
        #pragma unroll
        for (int i = 0; i < 4; ++i)
            #pragma unroll
            for (int j = 0; j < 4; ++j) acc[i][j] = 0.0f;
        float bssq = 0.0f;
        for (int kc = 0; kc < ND; kc += 16) {
            __syncthreads();
            float4 va = *(const float4*)(A + (size_t)(a0 + lrow) * ND + kc + lk4);
            float4 vb = *(const float4*)(B + (size_t)(j0 + lrow) * ND + kc + lk4);
            As[lk4 + 0][lrow] = va.x; As[lk4 + 1][lrow] = va.y;
            As[lk4 + 2][lrow] = va.z; As[lk4 + 3][lrow] = va.w;
            Bs[lk4 + 0][lrow] = vb.x; Bs[lk4 + 1][lrow] = vb.y;
            Bs[lk4 + 2][lrow] = vb.z; Bs[lk4 + 3][lrow] = vb.w;
            bssq += vb.x*vb.x + vb.y*vb.y + vb.z*vb.z + vb.w*vb.w;
            __syncthreads();
            #pragma unroll
            for (int k = 0; k < 16; ++k) {
                float4 av = *(const float4*)&As[k][ty4];
                float4 bv = *(const float4*)&Bs[k][tx4];
                float ar[4] = {av.x, av.y, av.z, av.w};
                float br[4] = {bv.x, bv.y, bv.z, bv.w};
                #pragma unroll
                for (int i = 0; i < 4; ++i)
                    #pragma unroll
                    for (int j = 0; j < 4; ++j)
                        acc[i][j] = fmaf(ar[i], br[j], acc[i][j]);
            }
        }
        bssq += __shfl_xor(bssq, 1); bssq += __shfl_xor(bssq, 2);
        __syncthreads();
        if ((tid & 3) == 0) {
            colRn[lrow]  = 1.0f / (sqrtf(bssq) + 1e-8f);
            colLab[lrow] = labels[j0 + lrow];
        }
        if (tid < 64) prevIdx[tid] = resIdx[tid];
        __syncthreads();
        #pragma unroll
        for (int i = 0; i < 4; ++i) {
            int r = ty4 + i;
            if (prevIdx[r] != INT_MAX) continue;
            float dg = aDg[r], mgv = aMg[r], rna = aRn[r];
            int la = aLab[r];
            #pragma unroll
            for (int j = 0; j < 4; ++j) {
                int c = tx4 + j;
                if (colLab[c] == la) continue;
                float v  = acc[i][j] * rna * colRn[c];
                float lm = v - dg + mgv;
                if (lm > 0.0f && lm < mgv) atomicMin(&resIdx[r], j0 + c);
            }
        }
        __syncthreads();
        #pragma unroll
        for (int i = 0; i < 4; ++i) {
            int r = ty4 + i;
            if (prevIdx[r] != INT_MAX) continue;
            int w = resIdx[r];
            if (w == INT_MAX) continue;
            int c = w - j0 - tx4;
            if (c < 0 || c > 3) continue;
            float v  = acc[i][c] * aRn[r] * colRn[tx4 + c];
            float lm = v - aDg[r] + aMg[r];
            atomicAdd(&blockAcc, lm);
        }
        __syncthreads();
        if (tid == 0) cnt = 0;
        __syncthreads();
        if (tid < 64 && resIdx[tid] == INT_MAX) atomicAdd(&cnt, 1);
        __syncthreads();
        unresolved = cnt;
        bandCols = j0 + 64;
        __syncthreads();
        if (unresolved <= 8) break;
    }
    if (unresolved > 0) {
        if (tid == 0) sCnt = 0;
        __syncthreads();
        if (tid < 64 && resIdx[tid] == INT_MAX) {
            int pos = atomicAdd(&sCnt, 1);
            sList[pos] = tid;
        }
        __syncthreads();
        int total = sCnt;
        for (int g0 = 0; g0 < total; g0 += 8) {
            int u = min(8, total - g0);
            if (u == 1)      stragScan<1>(A, B, labels, a0, u, bandCols, sList, g0, aRn, aDg, aMg, aLab, sMin8, &doneMask, &blockAcc);
            else if (u == 2) stragScan<2>(A, B, labels, a0, u, bandCols, sList, g0, aRn, aDg, aMg, aLab, sMin8, &doneMask, &blockAcc);
            else if (u <= 4) stragScan<4>(A, B, labels, a0, u, bandCols, sList, g0, aRn, aDg, aMg, aLab, sMin8, &doneMask, &blockAcc);
            else             stragScan<8>(A, B, labels, a0, u, bandCols, sList, g0, aRn, aDg, aMg, aLab, sMin8, &doneMask, &blockAcc);
            __syncthreads();
        }
    }
    if (tid == 0 && blockAcc != 0.0f) {
        float scale = (z >= 2) ? betap[0] : 1.0f;
        atomicAdd(out, blockAcc * scale);
    }
}

// ===========================================================================

extern "C" void kernel_launch(void* const* d_in, const int* in_sizes, int n_in,
                              void* d_out, int out_size, void* d_ws, size_t ws_size,
                              hipStream_t stream) {
    const float* img    = (const float*)d_in[0];
    const float* txt    = (const float*)d_in[1];
    const float* cr     = (const float*)d_in[2];
    const int*   labels = (const int*)  d_in[3];
    const int*   flagp  = (const int*)  d_in[4];
    const float* marg   = (const float*)d_in[5];
    const float* betap  = (const float*)d_in[6];
    float* out = (float*)d_out;
    (void)in_sizes; (void)n_in;

    const size_t REQ = (size_t)(6 * NB) * 4 + (size_t)(4 * NB) * 8 + 64 +
                       (size_t)(4 * NB) * 4;
    if (ws_size >= REQ) {
        float* wf = (float*)d_ws;
        float* rnImg = wf + 0 * NB;
        float* rnTxt = wf + 1 * NB;
        float* rnCr  = wf + 2 * NB;
        float* dgSim = wf + 3 * NB;
        float* dgCr  = wf + 4 * NB;
        float* mgCr  = wf + 5 * NB;
        unsigned long long* negIdx64 = (unsigned long long*)(wf + 6 * NB);
        int* stragCnt  = (int*)(negIdx64 + 4 * NB);
        int* stragList = stragCnt + 16;

        stats_k<<<dim3(NB / 16),              dim3(256), 0, stream>>>(
            img, txt, cr, marg, flagp,
            rnImg, rnTxt, rnCr, dgSim, dgCr, mgCr, negIdx64, stragCnt, out);
        band_k <<<dim3(NB / 64, 4),           dim3(256), 0, stream>>>(
            img, txt, cr, labels, flagp, marg, betap,
            rnImg, rnTxt, rnCr, dgSim, dgCr, mgCr, stragCnt, stragList, out);
        wina_k <<<dim3(WCHUNKS * WTILES, 4),  dim3(256), 0, stream>>>(
            img, txt, cr, labels, marg,
            rnImg, rnTxt, rnCr, dgSim, dgCr, mgCr,
            stragCnt, stragList, negIdx64);
        tail_k <<<dim3(TCHUNKS, 4),           dim3(256), 0, stream>>>(
            img, txt, cr, labels, marg,
            rnImg, rnTxt, rnCr, dgSim, dgCr, mgCr,
            stragCnt, stragList, negIdx64);
        final_k<<<dim3(NB / 256, 4),          dim3(256), 0, stream>>>(
            betap, stragCnt, stragList, negIdx64, out);
    } else {
        zero_k<<<dim3((out_size + 255) / 256), dim3(256), 0, stream>>>(out, out_size);
        mine_k<<<dim3(NB / 64, 4), dim3(256), 0, stream>>>(img, txt, cr, labels,
                                                           flagp, marg, betap, out);
    }
}